// Round 2
// baseline (905.830 us; speedup 1.0000x reference)
//
#include <hip/hip_runtime.h>
#include <hip/hip_bf16.h>
#include <stdint.h>

#define LOG2E 1.44269504088896340736f

typedef __attribute__((ext_vector_type(8))) short short8;
typedef __attribute__((ext_vector_type(4))) float f32x4;
typedef __attribute__((ext_vector_type(4))) unsigned short us4;

static __device__ __forceinline__ float bf2f(unsigned short u) {
    union { unsigned int i; float f; } v; v.i = ((unsigned int)u) << 16; return v.f;
}
static __device__ __forceinline__ unsigned short f2bf(float f) {
    __hip_bfloat16 h = __float2bfloat16(f);
    union { __hip_bfloat16 h; unsigned short u; } v; v.h = h; return v.u;
}

// global -> LDS direct copy, 16B per lane. LDS dest must be wave-uniform base
// (+ lane*16 implicit); global source is per-lane (guide §5, m104/m173).
#define GLL(gsrc, ldst) \
    __builtin_amdgcn_global_load_lds((const __attribute__((address_space(1))) unsigned int*)(gsrc), \
                                     (__attribute__((address_space(3))) unsigned int*)(ldst), 16, 0, 0)

// ---------------------------------------------------------------------------
// fp32 -> bf16 convert (vectorized)
// ---------------------------------------------------------------------------
__global__ __launch_bounds__(256) void conv_bf16(const float4* __restrict__ in,
                                                 us4* __restrict__ out, int n4) {
    int i = blockIdx.x * blockDim.x + threadIdx.x;
    int stride = gridDim.x * blockDim.x;
    for (; i < n4; i += stride) {
        float4 v = in[i];
        us4 o;
        o[0] = f2bf(v.x); o[1] = f2bf(v.y); o[2] = f2bf(v.z); o[3] = f2bf(v.w);
        out[i] = o;
    }
}

// ---------------------------------------------------------------------------
// W [K][M] fp32 -> WT [M][K] bf16 (64x64 tiles via LDS, padded)
// ---------------------------------------------------------------------------
__global__ __launch_bounds__(256) void transpose_w(const float* __restrict__ W,
                                                   unsigned short* __restrict__ WT,
                                                   int K, int M) {
    __shared__ unsigned short T[64][65];
    int m0 = blockIdx.x * 64, k0 = blockIdx.y * 64;
    int r = threadIdx.x >> 2, q = (threadIdx.x & 3) * 16;
    const float4* src = (const float4*)(W + (size_t)(k0 + r) * M + m0 + q);
#pragma unroll
    for (int j = 0; j < 4; j++) {
        float4 v = src[j];
        T[r][q + j * 4 + 0] = f2bf(v.x);
        T[r][q + j * 4 + 1] = f2bf(v.y);
        T[r][q + j * 4 + 2] = f2bf(v.z);
        T[r][q + j * 4 + 3] = f2bf(v.w);
    }
    __syncthreads();
    unsigned short tmp[16];
#pragma unroll
    for (int j = 0; j < 16; j++) tmp[j] = T[q + j][r];
    unsigned short* dst = WT + (size_t)(m0 + r) * K + k0 + q;
    *(short8*)dst = *(const short8*)tmp;
    *(short8*)(dst + 8) = *(const short8*)(tmp + 8);
}

// ---------------------------------------------------------------------------
// Shared 128x128x(K=1024) bf16 GEMM core. A [M,1024] row-major bf16,
// Bt [N,1024] row-major bf16 (i.e. B transposed). BK=64, single LDS buffer,
// global_load_lds staging with XOR-swizzle (slot ^= row&7) applied on the
// global SOURCE address (LDS dest linear) and on the ds_read side.
// ---------------------------------------------------------------------------
__device__ __forceinline__ void gemm_core(const unsigned short* __restrict__ A,
                                          const unsigned short* __restrict__ Bt,
                                          int brow, int bcol,
                                          unsigned short* As, unsigned short* Bs,
                                          f32x4 (&acc)[4][4]) {
    const int tid = threadIdx.x;
    const int w = tid >> 6, lane = tid & 63;
    const int g = lane >> 4, c = lane & 15;
    const int wr = (w >> 1) * 64, wc = (w & 1) * 64;

    for (int k0 = 0; k0 < 1024; k0 += 64) {
        __syncthreads();
#pragma unroll
        for (int i = 0; i < 4; i++) {
            int slot = i * 256 + tid;
            int row = slot >> 3, sub = slot & 7;
            int koff = k0 + ((sub ^ (row & 7)) << 3);
            GLL(A + (size_t)(brow + row) * 1024 + koff, As + (size_t)(i * 256 + w * 64) * 8);
            GLL(Bt + (size_t)(bcol + row) * 1024 + koff, Bs + (size_t)(i * 256 + w * 64) * 8);
        }
        __syncthreads();
#pragma unroll
        for (int kc = 0; kc < 2; kc++) {
            short8 a[4], b[4];
#pragma unroll
            for (int f = 0; f < 4; f++) {
                int rowA = wr + f * 16 + c;
                a[f] = *(const short8*)(As + (size_t)(rowA * 8 + ((kc * 4 + g) ^ (rowA & 7))) * 8);
                int rowB = wc + f * 16 + c;
                b[f] = *(const short8*)(Bs + (size_t)(rowB * 8 + ((kc * 4 + g) ^ (rowB & 7))) * 8);
            }
#pragma unroll
            for (int fi = 0; fi < 4; fi++)
#pragma unroll
                for (int fj = 0; fj < 4; fj++)
                    acc[fi][fj] = __builtin_amdgcn_mfma_f32_16x16x32_bf16(a[fi], b[fj], acc[fi][fj], 0, 0, 0);
        }
    }
}

// GEMM1: X[8192,1024] @ Wqkv -> q,k into qkv[8192,2048] (bf16), v transposed
// into vt[(b*16+h)*64+d][4096] (bf16).
__global__ __launch_bounds__(256) void gemm_qkv(const unsigned short* __restrict__ A,
                                                const unsigned short* __restrict__ Bt,
                                                unsigned short* __restrict__ qkv,
                                                unsigned short* __restrict__ vt) {
    __shared__ unsigned short As[128 * 64];
    __shared__ unsigned short Bs[128 * 64];
    const int tid = threadIdx.x;
    const int lane = tid & 63, w = tid >> 6;
    const int g = lane >> 4, c = lane & 15;
    const int brow = blockIdx.x * 128, bcol = blockIdx.y * 128;
    const int wr = (w >> 1) * 64, wc = (w & 1) * 64;

    f32x4 acc[4][4];
#pragma unroll
    for (int i = 0; i < 4; i++)
#pragma unroll
        for (int j = 0; j < 4; j++) acc[i][j] = (f32x4){0.f, 0.f, 0.f, 0.f};

    gemm_core(A, Bt, brow, bcol, As, Bs, acc);

    if (bcol < 2048) {  // q or k region -> qkv buffer
#pragma unroll
        for (int fi = 0; fi < 4; fi++) {
            int row = brow + wr + fi * 16 + g * 4;
#pragma unroll
            for (int fj = 0; fj < 4; fj++) {
                int col = bcol + wc + fj * 16 + c;
#pragma unroll
                for (int r = 0; r < 4; r++)
                    qkv[(size_t)(row + r) * 2048 + col] = f2bf(acc[fi][fj][r]);
            }
        }
    } else {  // v region -> transposed vt, 4 tokens packed per 8B store
        int b = brow >> 12;
        int nbase = (brow & 4095) + wr;
#pragma unroll
        for (int fi = 0; fi < 4; fi++) {
            int n0 = nbase + fi * 16 + g * 4;
#pragma unroll
            for (int fj = 0; fj < 4; fj++) {
                int hd = bcol - 2048 + wc + fj * 16 + c;
                us4 pk;
#pragma unroll
                for (int r = 0; r < 4; r++) pk[r] = f2bf(acc[fi][fj][r]);
                *(us4*)(vt + (size_t)(b * 1024 + hd) * 4096 + n0) = pk;
            }
        }
    }
}

// GEMM2: attn[8192,1024] @ Wout -> out fp32 [8192,1024]
__global__ __launch_bounds__(256) void gemm_out(const unsigned short* __restrict__ A,
                                                const unsigned short* __restrict__ Bt,
                                                float* __restrict__ C) {
    __shared__ unsigned short As[128 * 64];
    __shared__ unsigned short Bs[128 * 64];
    const int tid = threadIdx.x;
    const int lane = tid & 63, w = tid >> 6;
    const int g = lane >> 4, c = lane & 15;
    const int brow = blockIdx.x * 128, bcol = blockIdx.y * 128;
    const int wr = (w >> 1) * 64, wc = (w & 1) * 64;

    f32x4 acc[4][4];
#pragma unroll
    for (int i = 0; i < 4; i++)
#pragma unroll
        for (int j = 0; j < 4; j++) acc[i][j] = (f32x4){0.f, 0.f, 0.f, 0.f};

    gemm_core(A, Bt, brow, bcol, As, Bs, acc);

#pragma unroll
    for (int fi = 0; fi < 4; fi++) {
        int row = brow + wr + fi * 16 + g * 4;
#pragma unroll
        for (int fj = 0; fj < 4; fj++) {
            int col = bcol + wc + fj * 16 + c;
#pragma unroll
            for (int r = 0; r < 4; r++)
                C[(size_t)(row + r) * 1024 + col] = acc[fi][fj][r];
        }
    }
}

// ---------------------------------------------------------------------------
// per-(token,head) RMSNorm + RoPE on q and k, in place. One wave per unit,
// lane = head-dim element.
// ---------------------------------------------------------------------------
__global__ __launch_bounds__(256) void norm_rope(unsigned short* __restrict__ qkv,
                                                 const float* __restrict__ cosb,
                                                 const float* __restrict__ sinb,
                                                 const float* __restrict__ gq,
                                                 const float* __restrict__ gk) {
    int u = blockIdx.x * 4 + (threadIdx.x >> 6);
    int lane = threadIdx.x & 63;
    int t = u >> 5, rest = u & 31, h = rest >> 1, qk = rest & 1;
    int n = t & 4095;
    unsigned short* p = qkv + (size_t)t * 2048 + qk * 1024 + h * 64 + lane;
    float x = bf2f(*p);
    float ss = x * x;
#pragma unroll
    for (int m = 1; m < 64; m <<= 1) ss += __shfl_xor(ss, m, 64);
    float rr = rsqrtf(ss * 0.015625f + 1e-6f);
    float xn = x * rr * (qk ? gk[lane] : gq[lane]);
    float other = __shfl_xor(xn, 32, 64);
    float cv = cosb[n * 64 + lane], sv = sinb[n * 64 + lane];
    float rh = (lane < 32) ? -other : other;
    *p = f2bf(xn * cv + rh * sv);
}

// ---------------------------------------------------------------------------
// Flash attention. grid = (qtile=32, bh=32). 4 waves x 32 q-rows. KV tiles of
// 64 staged to swizzled LDS. Online softmax in fp32, P via per-wave padded LDS.
// ---------------------------------------------------------------------------
__global__ __launch_bounds__(256) void attn_fwd(const unsigned short* __restrict__ qkv,
                                                const unsigned short* __restrict__ vt,
                                                unsigned short* __restrict__ attn) {
    __shared__ unsigned short Ks[64 * 64];
    __shared__ unsigned short Vs[64 * 64];
    __shared__ unsigned short Ps[4][32 * 72];
    const int tid = threadIdx.x;
    const int w = tid >> 6, lane = tid & 63;
    const int g = lane >> 4, c = lane & 15;
    const int qt = blockIdx.x, bh = blockIdx.y;
    const int b = bh >> 4, h = bh & 15;
    const size_t tokbase = (size_t)b * 4096;

    // Q fragments, pre-scaled by 1/sqrt(D)=0.125 (exact in bf16)
    short8 qf[2][2];
#pragma unroll
    for (int rf = 0; rf < 2; rf++)
#pragma unroll
        for (int kc = 0; kc < 2; kc++) {
            int qrow = qt * 128 + w * 32 + rf * 16 + c;
            const unsigned short* src = qkv + (tokbase + qrow) * 2048 + h * 64 + kc * 32 + g * 8;
            short8 v = *(const short8*)src;
#pragma unroll
            for (int j = 0; j < 8; j++)
                v[j] = (short)f2bf(bf2f((unsigned short)v[j]) * 0.125f);
            qf[rf][kc] = v;
        }

    f32x4 o[2][4];
    float m_run[2][4], l_run[2][4];
#pragma unroll
    for (int rf = 0; rf < 2; rf++) {
#pragma unroll
        for (int fd = 0; fd < 4; fd++) o[rf][fd] = (f32x4){0.f, 0.f, 0.f, 0.f};
#pragma unroll
        for (int r = 0; r < 4; r++) { m_run[rf][r] = -__builtin_inff(); l_run[rf][r] = 0.f; }
    }

    unsigned short* Pw = Ps[w];

    for (int kv0 = 0; kv0 < 4096; kv0 += 64) {
        __syncthreads();
#pragma unroll
        for (int i = 0; i < 2; i++) {
            int slot = i * 256 + tid;
            int row = slot >> 3, sub = slot & 7;
            GLL(qkv + (tokbase + kv0 + row) * 2048 + 1024 + h * 64 + ((sub ^ (row & 7)) << 3),
                Ks + (size_t)(i * 256 + w * 64) * 8);
            GLL(vt + ((size_t)bh * 64 + row) * 4096 + kv0 + ((sub ^ (row & 7)) << 3),
                Vs + (size_t)(i * 256 + w * 64) * 8);
        }
        __syncthreads();

        // S = Q K^T (pre-scaled)
        short8 kb[4][2];
#pragma unroll
        for (int fk = 0; fk < 4; fk++)
#pragma unroll
            for (int kc = 0; kc < 2; kc++) {
                int row = fk * 16 + c;
                kb[fk][kc] = *(const short8*)(Ks + (size_t)(row * 8 + ((kc * 4 + g) ^ (row & 7))) * 8);
            }
        f32x4 s[2][4];
#pragma unroll
        for (int rf = 0; rf < 2; rf++)
#pragma unroll
            for (int fk = 0; fk < 4; fk++) {
                f32x4 acc = (f32x4){0.f, 0.f, 0.f, 0.f};
                acc = __builtin_amdgcn_mfma_f32_16x16x32_bf16(qf[rf][0], kb[fk][0], acc, 0, 0, 0);
                acc = __builtin_amdgcn_mfma_f32_16x16x32_bf16(qf[rf][1], kb[fk][1], acc, 0, 0, 0);
                s[rf][fk] = acc;
            }

        // online softmax (rows live in 16-lane groups; reduce over c)
#pragma unroll
        for (int rf = 0; rf < 2; rf++)
#pragma unroll
            for (int r = 0; r < 4; r++) {
                float mx = fmaxf(fmaxf(s[rf][0][r], s[rf][1][r]), fmaxf(s[rf][2][r], s[rf][3][r]));
#pragma unroll
                for (int msk = 1; msk < 16; msk <<= 1) mx = fmaxf(mx, __shfl_xor(mx, msk, 64));
                float mn = fmaxf(m_run[rf][r], mx);
                float alpha = exp2f((m_run[rf][r] - mn) * LOG2E);
                m_run[rf][r] = mn;
                float rs = 0.f;
#pragma unroll
                for (int fk = 0; fk < 4; fk++) {
                    float pv = exp2f((s[rf][fk][r] - mn) * LOG2E);
                    s[rf][fk][r] = pv;
                    rs += pv;
                }
#pragma unroll
                for (int msk = 1; msk < 16; msk <<= 1) rs += __shfl_xor(rs, msk, 64);
                l_run[rf][r] = l_run[rf][r] * alpha + rs;
#pragma unroll
                for (int fd = 0; fd < 4; fd++) o[rf][fd][r] *= alpha;
                int prow = rf * 16 + g * 4 + r;
#pragma unroll
                for (int fk = 0; fk < 4; fk++)
                    Pw[prow * 72 + fk * 16 + c] = f2bf(s[rf][fk][r]);
            }

        // O += P V
        short8 pa[2][2];
#pragma unroll
        for (int rf = 0; rf < 2; rf++)
#pragma unroll
            for (int kc = 0; kc < 2; kc++)
                pa[rf][kc] = *(const short8*)(Pw + (rf * 16 + c) * 72 + kc * 32 + g * 8);
        short8 vb[4][2];
#pragma unroll
        for (int fd = 0; fd < 4; fd++)
#pragma unroll
            for (int kc = 0; kc < 2; kc++) {
                int row = fd * 16 + c;
                vb[fd][kc] = *(const short8*)(Vs + (size_t)(row * 8 + ((kc * 4 + g) ^ (row & 7))) * 8);
            }
#pragma unroll
        for (int rf = 0; rf < 2; rf++)
#pragma unroll
            for (int fd = 0; fd < 4; fd++) {
                o[rf][fd] = __builtin_amdgcn_mfma_f32_16x16x32_bf16(pa[rf][0], vb[fd][0], o[rf][fd], 0, 0, 0);
                o[rf][fd] = __builtin_amdgcn_mfma_f32_16x16x32_bf16(pa[rf][1], vb[fd][1], o[rf][fd], 0, 0, 0);
            }
    }

    // epilogue: O / l -> attn buffer [token][h*64+d] bf16
#pragma unroll
    for (int rf = 0; rf < 2; rf++)
#pragma unroll
        for (int r = 0; r < 4; r++) {
            float inv = 1.f / l_run[rf][r];
            int token = qt * 128 + w * 32 + rf * 16 + g * 4 + r;
#pragma unroll
            for (int fd = 0; fd < 4; fd++) {
                int col = h * 64 + fd * 16 + c;
                attn[(tokbase + token) * 1024 + col] = f2bf(o[rf][fd][r] * inv);
            }
        }
}

// ---------------------------------------------------------------------------
extern "C" void kernel_launch(void* const* d_in, const int* in_sizes, int n_in,
                              void* d_out, int out_size, void* d_ws, size_t ws_size,
                              hipStream_t stream) {
    const float* hs   = (const float*)d_in[0];
    const float* cosb = (const float*)d_in[1];
    const float* sinb = (const float*)d_in[2];
    const float* wqkv = (const float*)d_in[3];
    const float* wout = (const float*)d_in[4];
    const float* gq   = (const float*)d_in[5];
    const float* gk   = (const float*)d_in[6];
    float* out = (float*)d_out;

    char* ws = (char*)d_ws;
    unsigned short* Xb    = (unsigned short*)(ws);               // 8192*1024*2  = 16 MiB
    unsigned short* WqkvT = (unsigned short*)(ws + 16777216);    // 3072*1024*2  =  6 MiB
    unsigned short* WoutT = (unsigned short*)(ws + 23068672);    // 1024*1024*2  =  2 MiB
    unsigned short* qkv   = (unsigned short*)(ws + 25165824);    // 8192*2048*2  = 32 MiB
    unsigned short* vt    = (unsigned short*)(ws + 58720256);    // 2048*4096*2  = 16 MiB
    unsigned short* attn  = (unsigned short*)(ws + 75497472);    // 8192*1024*2  = 16 MiB

    conv_bf16<<<4096, 256, 0, stream>>>((const float4*)hs, (us4*)Xb, (8192 * 1024) / 4);
    transpose_w<<<dim3(48, 16), 256, 0, stream>>>(wqkv, WqkvT, 1024, 3072);
    transpose_w<<<dim3(16, 16), 256, 0, stream>>>(wout, WoutT, 1024, 1024);
    gemm_qkv<<<dim3(64, 24), 256, 0, stream>>>(Xb, WqkvT, qkv, vt);
    norm_rope<<<65536, 256, 0, stream>>>(qkv, cosb, sinb, gq, gk);
    attn_fwd<<<dim3(32, 32), 256, 0, stream>>>(qkv, vt, attn);
    gemm_out<<<dim3(64, 8), 256, 0, stream>>>(attn, WoutT, out);
}

// Round 5
// 499.348 us; speedup vs baseline: 1.8140x; 1.8140x over previous
//
#include <hip/hip_runtime.h>
#include <hip/hip_bf16.h>
#include <stdint.h>

#define LOG2E 1.44269504088896340736f

typedef __attribute__((ext_vector_type(8))) short short8;
typedef __attribute__((ext_vector_type(4))) float f32x4;
typedef __attribute__((ext_vector_type(16))) float f32x16;
typedef __attribute__((ext_vector_type(4))) unsigned short us4;

static __device__ __forceinline__ float bf2f(unsigned short u) {
    union { unsigned int i; float f; } v; v.i = ((unsigned int)u) << 16; return v.f;
}
static __device__ __forceinline__ unsigned short f2bf(float f) {
    __hip_bfloat16 h = __float2bfloat16(f);
    union { __hip_bfloat16 h; unsigned short u; } v; v.h = h; return v.u;
}
static __device__ __forceinline__ unsigned int pack_bf2(float lo, float hi) {
    return ((unsigned int)f2bf(hi) << 16) | (unsigned int)f2bf(lo);
}

// global -> LDS direct copy, 16B per lane. LDS dest is wave-uniform base
// (+ lane*16 implicit); global source is per-lane (guide §5, m104/m173).
#define GLL(gsrc, ldst) \
    __builtin_amdgcn_global_load_lds((const __attribute__((address_space(1))) unsigned int*)(gsrc), \
                                     (__attribute__((address_space(3))) unsigned int*)(ldst), 16, 0, 0)

// ---------------------------------------------------------------------------
// fp32 -> bf16 convert (vectorized)
// ---------------------------------------------------------------------------
__global__ __launch_bounds__(256) void conv_bf16(const float4* __restrict__ in,
                                                 us4* __restrict__ out, int n4) {
    int i = blockIdx.x * blockDim.x + threadIdx.x;
    int stride = gridDim.x * blockDim.x;
    for (; i < n4; i += stride) {
        float4 v = in[i];
        us4 o;
        o[0] = f2bf(v.x); o[1] = f2bf(v.y); o[2] = f2bf(v.z); o[3] = f2bf(v.w);
        out[i] = o;
    }
}

// ---------------------------------------------------------------------------
// W [K][M] fp32 -> WT [M][K] bf16 (64x64 tiles via LDS, padded)
// ---------------------------------------------------------------------------
__global__ __launch_bounds__(256) void transpose_w(const float* __restrict__ W,
                                                   unsigned short* __restrict__ WT,
                                                   int K, int M) {
    __shared__ unsigned short T[64][65];
    int m0 = blockIdx.x * 64, k0 = blockIdx.y * 64;
    int r = threadIdx.x >> 2, q = (threadIdx.x & 3) * 16;
    const float4* src = (const float4*)(W + (size_t)(k0 + r) * M + m0 + q);
#pragma unroll
    for (int j = 0; j < 4; j++) {
        float4 v = src[j];
        T[r][q + j * 4 + 0] = f2bf(v.x);
        T[r][q + j * 4 + 1] = f2bf(v.y);
        T[r][q + j * 4 + 2] = f2bf(v.z);
        T[r][q + j * 4 + 3] = f2bf(v.w);
    }
    __syncthreads();
    unsigned short tmp[16];
#pragma unroll
    for (int j = 0; j < 16; j++) tmp[j] = T[q + j][r];
    unsigned short* dst = WT + (size_t)(m0 + r) * K + k0 + q;
    *(short8*)dst = *(const short8*)tmp;
    *(short8*)(dst + 8) = *(const short8*)(tmp + 8);
}

// ---------------------------------------------------------------------------
// Shared 128x128x(K=1024) bf16 GEMM core (m97 structure).
// ---------------------------------------------------------------------------
__device__ __forceinline__ void gemm_core(const unsigned short* __restrict__ A,
                                          const unsigned short* __restrict__ Bt,
                                          int brow, int bcol,
                                          unsigned short* As, unsigned short* Bs,
                                          f32x4 (&acc)[4][4]) {
    const int tid = threadIdx.x;
    const int w = tid >> 6, lane = tid & 63;
    const int g = lane >> 4, c = lane & 15;
    const int wr = (w >> 1) * 64, wc = (w & 1) * 64;

    for (int k0 = 0; k0 < 1024; k0 += 64) {
        __syncthreads();
#pragma unroll
        for (int i = 0; i < 4; i++) {
            int slot = i * 256 + tid;
            int row = slot >> 3, sub = slot & 7;
            int koff = k0 + ((sub ^ (row & 7)) << 3);
            GLL(A + (size_t)(brow + row) * 1024 + koff, As + (size_t)(i * 256 + w * 64) * 8);
            GLL(Bt + (size_t)(bcol + row) * 1024 + koff, Bs + (size_t)(i * 256 + w * 64) * 8);
        }
        __syncthreads();
#pragma unroll
        for (int kc = 0; kc < 2; kc++) {
            short8 a[4], b[4];
#pragma unroll
            for (int f = 0; f < 4; f++) {
                int rowA = wr + f * 16 + c;
                a[f] = *(const short8*)(As + (size_t)(rowA * 8 + ((kc * 4 + g) ^ (rowA & 7))) * 8);
                int rowB = wc + f * 16 + c;
                b[f] = *(const short8*)(Bs + (size_t)(rowB * 8 + ((kc * 4 + g) ^ (rowB & 7))) * 8);
            }
#pragma unroll
            for (int fi = 0; fi < 4; fi++)
#pragma unroll
                for (int fj = 0; fj < 4; fj++)
                    acc[fi][fj] = __builtin_amdgcn_mfma_f32_16x16x32_bf16(a[fi], b[fj], acc[fi][fj], 0, 0, 0);
        }
    }
}

// GEMM1: X[8192,1024] @ Wqkv -> q,k into qkv[8192,2048] (bf16), v transposed
// into vt[(b*16+h)*64+d][4096] (bf16).
__global__ __launch_bounds__(256) void gemm_qkv(const unsigned short* __restrict__ A,
                                                const unsigned short* __restrict__ Bt,
                                                unsigned short* __restrict__ qkv,
                                                unsigned short* __restrict__ vt) {
    __shared__ unsigned short As[128 * 64];
    __shared__ unsigned short Bs[128 * 64];
    const int tid = threadIdx.x;
    const int lane = tid & 63, w = tid >> 6;
    const int g = lane >> 4, c = lane & 15;
    const int brow = blockIdx.x * 128, bcol = blockIdx.y * 128;
    const int wr = (w >> 1) * 64, wc = (w & 1) * 64;

    f32x4 acc[4][4];
#pragma unroll
    for (int i = 0; i < 4; i++)
#pragma unroll
        for (int j = 0; j < 4; j++) acc[i][j] = (f32x4){0.f, 0.f, 0.f, 0.f};

    gemm_core(A, Bt, brow, bcol, As, Bs, acc);

    if (bcol < 2048) {  // q or k region -> qkv buffer
#pragma unroll
        for (int fi = 0; fi < 4; fi++) {
            int row = brow + wr + fi * 16 + g * 4;
#pragma unroll
            for (int fj = 0; fj < 4; fj++) {
                int col = bcol + wc + fj * 16 + c;
#pragma unroll
                for (int r = 0; r < 4; r++)
                    qkv[(size_t)(row + r) * 2048 + col] = f2bf(acc[fi][fj][r]);
            }
        }
    } else {  // v region -> transposed vt, 4 tokens packed per 8B store
        int b = brow >> 12;
        int nbase = (brow & 4095) + wr;
#pragma unroll
        for (int fi = 0; fi < 4; fi++) {
            int n0 = nbase + fi * 16 + g * 4;
#pragma unroll
            for (int fj = 0; fj < 4; fj++) {
                int hd = bcol - 2048 + wc + fj * 16 + c;
                us4 pk;
#pragma unroll
                for (int r = 0; r < 4; r++) pk[r] = f2bf(acc[fi][fj][r]);
                *(us4*)(vt + (size_t)(b * 1024 + hd) * 4096 + n0) = pk;
            }
        }
    }
}

// GEMM2: attn[8192,1024] @ Wout -> out fp32 [8192,1024]
__global__ __launch_bounds__(256) void gemm_out(const unsigned short* __restrict__ A,
                                                const unsigned short* __restrict__ Bt,
                                                float* __restrict__ C) {
    __shared__ unsigned short As[128 * 64];
    __shared__ unsigned short Bs[128 * 64];
    const int tid = threadIdx.x;
    const int lane = tid & 63, w = tid >> 6;
    const int g = lane >> 4, c = lane & 15;
    const int brow = blockIdx.x * 128, bcol = blockIdx.y * 128;
    const int wr = (w >> 1) * 64, wc = (w & 1) * 64;

    f32x4 acc[4][4];
#pragma unroll
    for (int i = 0; i < 4; i++)
#pragma unroll
        for (int j = 0; j < 4; j++) acc[i][j] = (f32x4){0.f, 0.f, 0.f, 0.f};

    gemm_core(A, Bt, brow, bcol, As, Bs, acc);

#pragma unroll
    for (int fi = 0; fi < 4; fi++) {
        int row = brow + wr + fi * 16 + g * 4;
#pragma unroll
        for (int fj = 0; fj < 4; fj++) {
            int col = bcol + wc + fj * 16 + c;
#pragma unroll
            for (int r = 0; r < 4; r++)
                C[(size_t)(row + r) * 1024 + col] = acc[fi][fj][r];
        }
    }
}

// ---------------------------------------------------------------------------
// per-(token,head) RMSNorm + RoPE on q and k, in place.
// ---------------------------------------------------------------------------
__global__ __launch_bounds__(256) void norm_rope(unsigned short* __restrict__ qkv,
                                                 const float* __restrict__ cosb,
                                                 const float* __restrict__ sinb,
                                                 const float* __restrict__ gq,
                                                 const float* __restrict__ gk) {
    int u = blockIdx.x * 4 + (threadIdx.x >> 6);
    int lane = threadIdx.x & 63;
    int t = u >> 5, rest = u & 31, h = rest >> 1, qk = rest & 1;
    int n = t & 4095;
    unsigned short* p = qkv + (size_t)t * 2048 + qk * 1024 + h * 64 + lane;
    float x = bf2f(*p);
    float ss = x * x;
#pragma unroll
    for (int m = 1; m < 64; m <<= 1) ss += __shfl_xor(ss, m, 64);
    float rr = rsqrtf(ss * 0.015625f + 1e-6f);
    float xn = x * rr * (qk ? gk[lane] : gq[lane]);
    float other = __shfl_xor(xn, 32, 64);
    float cv = cosb[n * 64 + lane], sv = sinb[n * 64 + lane];
    float rh = (lane < 32) ? -other : other;
    *p = f2bf(xn * cv + rh * sv);
}

// ---------------------------------------------------------------------------
// Flash attention v2: swapped QK^T on 32x32x16 MFMA, in-register softmax.
// Grid: 512 blocks (XCD-chunk remapped), 4 waves x 64 q-rows = 256 q/block.
// KV tile 64; K/V in LDS as [d-or-kv slice(8)][row(64)][8 bf16] -> every
// ds_read_b128 is a dense 512B run (conflict-free). Double-buffered, one
// barrier per tile; prefetch issued before compute (T3-lite).
// Layout facts used (m74/m101): 32x32 C/D: col=lane&31,
// row=(reg&3)+8*(reg>>2)+4*(lane>>5); A: row=lane&31,k=(lane>>5)*8+j;
// B: col=lane&31,k=(lane>>5)*8+j.
// ---------------------------------------------------------------------------
__global__ __launch_bounds__(256, 2) void attn_fwd(const unsigned short* __restrict__ qkv,
                                                   const unsigned short* __restrict__ vt,
                                                   unsigned short* __restrict__ attn) {
    __shared__ unsigned short Ks[2][4096];  // [buf][(dslice*64+kv)*8]
    __shared__ unsigned short Vs[2][4096];  // [buf][(kvslice*64+d)*8]
    const int tid = threadIdx.x;
    const int w = tid >> 6, lane = tid & 63;
    const int c31 = lane & 31, hi = lane >> 5;

    // XCD-chunked bijective remap: 512 blocks, 64 per XCD, bh-major chunks.
    int logical = (blockIdx.x & 7) * 64 + (blockIdx.x >> 3);
    const int bh = logical >> 4, qt = logical & 15;
    const int b = bh >> 4, h = bh & 15;
    const size_t tokbase = (size_t)b * 4096;
    const int q0 = qt * 256 + w * 64;

    // Q fragments [qsub][slice], pre-scaled by 0.125 (exact in bf16)
    short8 qf[2][4];
#pragma unroll
    for (int qs = 0; qs < 2; qs++)
#pragma unroll
        for (int sl = 0; sl < 4; sl++) {
            const unsigned short* src =
                qkv + (tokbase + q0 + qs * 32 + c31) * 2048 + h * 64 + sl * 16 + hi * 8;
            short8 v = *(const short8*)src;
#pragma unroll
            for (int j = 0; j < 8; j++)
                v[j] = (short)f2bf(bf2f((unsigned short)v[j]) * 0.125f);
            qf[qs][sl] = v;
        }

    f32x16 o[2][2];  // [qsub][dsub], O^T[d][q]
#pragma unroll
    for (int qs = 0; qs < 2; qs++)
#pragma unroll
        for (int ds = 0; ds < 2; ds++)
#pragma unroll
            for (int r = 0; r < 16; r++) o[qs][ds][r] = 0.f;
    float m_run[2] = {-__builtin_inff(), -__builtin_inff()};
    float l_run[2] = {0.f, 0.f};

    // stage tile (kv0) into buffer bi: wave w handles slices {w, 4+w}
#define STAGE_KV(bi, kv0)                                                                     \
    {                                                                                          \
        _Pragma("unroll") for (int i = 0; i < 2; i++) {                                        \
            int s2 = i * 4 + w;                                                                \
            GLL(qkv + (tokbase + (kv0) + lane) * 2048 + 1024 + h * 64 + s2 * 8,                \
                &Ks[bi][(size_t)s2 * 512]);                                                    \
            GLL(vt + ((size_t)(bh * 64 + lane)) * 4096 + (kv0) + s2 * 8,                       \
                &Vs[bi][(size_t)s2 * 512]);                                                    \
        }                                                                                      \
    }

    STAGE_KV(0, 0);
    int cur = 0;

    for (int t = 0; t < 64; t++) {
        __syncthreads();  // stage(cur) visible; prev reads done
        if (t < 63) STAGE_KV(cur ^ 1, (t + 1) * 64);

        // ---- K fragments + QK^T (S[kv][q], swapped) ----
        short8 kf[2][4];
#pragma unroll
        for (int m = 0; m < 2; m++)
#pragma unroll
            for (int sl = 0; sl < 4; sl++)
                kf[m][sl] = *(const short8*)&Ks[cur][(size_t)(((sl * 2 + hi) * 64) + m * 32 + c31) * 8];

        f32x16 sacc[2][2];
#pragma unroll
        for (int qs = 0; qs < 2; qs++)
#pragma unroll
            for (int m = 0; m < 2; m++) {
                f32x16 a;
#pragma unroll
                for (int r = 0; r < 16; r++) a[r] = 0.f;
#pragma unroll
                for (int sl = 0; sl < 4; sl++)
                    a = __builtin_amdgcn_mfma_f32_32x32x16_bf16(kf[m][sl], qf[qs][sl], a, 0, 0, 0);
                sacc[qs][m] = a;
            }

        // ---- softmax + P pack per qsub ----
        short8 pf[2][4];  // [qsub][kvslice] B-operand fragments
#pragma unroll
        for (int qs = 0; qs < 2; qs++) {
            float mx = sacc[qs][0][0];
#pragma unroll
            for (int m = 0; m < 2; m++)
#pragma unroll
                for (int r = 0; r < 16; r++)
                    if (m | r) mx = fmaxf(mx, sacc[qs][m][r]);
            mx = fmaxf(mx, __shfl_xor(mx, 32, 64));
            float mn = fmaxf(m_run[qs], mx);
            float alpha = exp2f((m_run[qs] - mn) * LOG2E);
            m_run[qs] = mn;
            float nb = -mn * LOG2E;
            float p[2][16];
            float rs = 0.f;
#pragma unroll
            for (int m = 0; m < 2; m++)
#pragma unroll
                for (int r = 0; r < 16; r++) {
                    float e = exp2f(fmaf(sacc[qs][m][r], LOG2E, nb));
                    p[m][r] = e;
                    rs += e;
                }
            rs += __shfl_xor(rs, 32, 64);
            l_run[qs] = l_run[qs] * alpha + rs;
#pragma unroll
            for (int ds = 0; ds < 2; ds++)
#pragma unroll
                for (int r = 0; r < 16; r++) o[qs][ds][r] *= alpha;

            // pack pairs: q2[m][w8] = bf16x2 of kv pair; exchange halves
#pragma unroll
            for (int m = 0; m < 2; m++) {
                unsigned int q2[8];
#pragma unroll
                for (int w8 = 0; w8 < 8; w8++)
                    q2[w8] = pack_bf2(p[m][2 * w8], p[m][2 * w8 + 1]);
                unsigned int x0 = hi ? q2[0] : q2[2];
                unsigned int x1 = hi ? q2[1] : q2[3];
                unsigned int x2 = hi ? q2[4] : q2[6];
                unsigned int x3 = hi ? q2[5] : q2[7];
                unsigned int r0 = (unsigned int)__shfl_xor((int)x0, 32, 64);
                unsigned int r1 = (unsigned int)__shfl_xor((int)x1, 32, 64);
                unsigned int r2 = (unsigned int)__shfl_xor((int)x2, 32, 64);
                unsigned int r3 = (unsigned int)__shfl_xor((int)x3, 32, 64);
                union { unsigned int u[4]; short8 s; } f0, f1;
                f0.u[0] = hi ? r0 : q2[0];
                f0.u[1] = hi ? r1 : q2[1];
                f0.u[2] = hi ? q2[2] : r0;
                f0.u[3] = hi ? q2[3] : r1;
                f1.u[0] = hi ? r2 : q2[4];
                f1.u[1] = hi ? r3 : q2[5];
                f1.u[2] = hi ? q2[6] : r2;
                f1.u[3] = hi ? q2[7] : r3;
                pf[qs][2 * m] = f0.s;
                pf[qs][2 * m + 1] = f1.s;
            }
        }

        // ---- PV: O^T[d][q] += V^T[d][kv] . P ----
#pragma unroll
        for (int ds = 0; ds < 2; ds++)
#pragma unroll
            for (int kvs = 0; kvs < 4; kvs++) {
                short8 vf = *(const short8*)&Vs[cur][(size_t)(((kvs * 2 + hi) * 64) + ds * 32 + c31) * 8];
                o[0][ds] = __builtin_amdgcn_mfma_f32_32x32x16_bf16(vf, pf[0][kvs], o[0][ds], 0, 0, 0);
                o[1][ds] = __builtin_amdgcn_mfma_f32_32x32x16_bf16(vf, pf[1][kvs], o[1][ds], 0, 0, 0);
            }
        cur ^= 1;
    }

    // ---- epilogue: O/l -> attn[token][h*64+d] bf16 ----
#pragma unroll
    for (int qs = 0; qs < 2; qs++) {
        float inv = 1.f / l_run[qs];
        int token = q0 + qs * 32 + c31;
#pragma unroll
        for (int ds = 0; ds < 2; ds++)
#pragma unroll
            for (int rb = 0; rb < 4; rb++) {
                us4 pk;
#pragma unroll
                for (int j = 0; j < 4; j++) pk[j] = f2bf(o[qs][ds][rb * 4 + j] * inv);
                *(us4*)(attn + (tokbase + token) * 1024 + h * 64 + ds * 32 + rb * 8 + hi * 4) = pk;
            }
    }
#undef STAGE_KV
}

// ---------------------------------------------------------------------------
extern "C" void kernel_launch(void* const* d_in, const int* in_sizes, int n_in,
                              void* d_out, int out_size, void* d_ws, size_t ws_size,
                              hipStream_t stream) {
    const float* hs   = (const float*)d_in[0];
    const float* cosb = (const float*)d_in[1];
    const float* sinb = (const float*)d_in[2];
    const float* wqkv = (const float*)d_in[3];
    const float* wout = (const float*)d_in[4];
    const float* gq   = (const float*)d_in[5];
    const float* gk   = (const float*)d_in[6];
    float* out = (float*)d_out;

    char* ws = (char*)d_ws;
    unsigned short* Xb    = (unsigned short*)(ws);               // 8192*1024*2  = 16 MiB
    unsigned short* WqkvT = (unsigned short*)(ws + 16777216);    // 3072*1024*2  =  6 MiB
    unsigned short* WoutT = (unsigned short*)(ws + 23068672);    // 1024*1024*2  =  2 MiB
    unsigned short* qkv   = (unsigned short*)(ws + 25165824);    // 8192*2048*2  = 32 MiB
    unsigned short* vt    = (unsigned short*)(ws + 58720256);    // 2048*4096*2  = 16 MiB
    unsigned short* attn  = (unsigned short*)(ws + 75497472);    // 8192*1024*2  = 16 MiB

    conv_bf16<<<4096, 256, 0, stream>>>((const float4*)hs, (us4*)Xb, (8192 * 1024) / 4);
    transpose_w<<<dim3(48, 16), 256, 0, stream>>>(wqkv, WqkvT, 1024, 3072);
    transpose_w<<<dim3(16, 16), 256, 0, stream>>>(wout, WoutT, 1024, 1024);
    gemm_qkv<<<dim3(64, 24), 256, 0, stream>>>(Xb, WqkvT, qkv, vt);
    norm_rope<<<65536, 256, 0, stream>>>(qkv, cosb, sinb, gq, gk);
    attn_fwd<<<512, 256, 0, stream>>>(qkv, vt, attn);
    gemm_out<<<dim3(64, 8), 256, 0, stream>>>(attn, WoutT, out);
}

// Round 6
// 419.057 us; speedup vs baseline: 2.1616x; 1.1916x over previous
//
#include <hip/hip_runtime.h>
#include <hip/hip_bf16.h>
#include <stdint.h>

#define LOG2E 1.44269504088896340736f

typedef __attribute__((ext_vector_type(8))) short short8;
typedef __attribute__((ext_vector_type(4))) float f32x4;
typedef __attribute__((ext_vector_type(16))) float f32x16;
typedef __attribute__((ext_vector_type(4))) unsigned short us4;

static __device__ __forceinline__ float bf2f(unsigned short u) {
    union { unsigned int i; float f; } v; v.i = ((unsigned int)u) << 16; return v.f;
}
static __device__ __forceinline__ unsigned short f2bf(float f) {
    __hip_bfloat16 h = __float2bfloat16(f);
    union { __hip_bfloat16 h; unsigned short u; } v; v.h = h; return v.u;
}

// global -> LDS direct copy, 16B per lane. LDS dest is wave-uniform base
// (+ lane*16 implicit); global source is per-lane (guide §5, m104/m173).
#define GLL(gsrc, ldst) \
    __builtin_amdgcn_global_load_lds((const __attribute__((address_space(1))) unsigned int*)(gsrc), \
                                     (__attribute__((address_space(3))) unsigned int*)(ldst), 16, 0, 0)

// ---------------------------------------------------------------------------
// fp32 -> bf16 convert (vectorized)
// ---------------------------------------------------------------------------
__global__ __launch_bounds__(256) void conv_bf16(const float4* __restrict__ in,
                                                 us4* __restrict__ out, int n4) {
    int i = blockIdx.x * blockDim.x + threadIdx.x;
    int stride = gridDim.x * blockDim.x;
    for (; i < n4; i += stride) {
        float4 v = in[i];
        us4 o;
        o[0] = f2bf(v.x); o[1] = f2bf(v.y); o[2] = f2bf(v.z); o[3] = f2bf(v.w);
        out[i] = o;
    }
}

// ---------------------------------------------------------------------------
// W [K][M] fp32 -> WT [M][K] bf16 (64x64 tiles via LDS, padded)
// ---------------------------------------------------------------------------
__global__ __launch_bounds__(256) void transpose_w(const float* __restrict__ W,
                                                   unsigned short* __restrict__ WT,
                                                   int K, int M) {
    __shared__ unsigned short T[64][65];
    int m0 = blockIdx.x * 64, k0 = blockIdx.y * 64;
    int r = threadIdx.x >> 2, q = (threadIdx.x & 3) * 16;
    const float4* src = (const float4*)(W + (size_t)(k0 + r) * M + m0 + q);
#pragma unroll
    for (int j = 0; j < 4; j++) {
        float4 v = src[j];
        T[r][q + j * 4 + 0] = f2bf(v.x);
        T[r][q + j * 4 + 1] = f2bf(v.y);
        T[r][q + j * 4 + 2] = f2bf(v.z);
        T[r][q + j * 4 + 3] = f2bf(v.w);
    }
    __syncthreads();
    unsigned short tmp[16];
#pragma unroll
    for (int j = 0; j < 16; j++) tmp[j] = T[q + j][r];
    unsigned short* dst = WT + (size_t)(m0 + r) * K + k0 + q;
    *(short8*)dst = *(const short8*)tmp;
    *(short8*)(dst + 8) = *(const short8*)(tmp + 8);
}

// ---------------------------------------------------------------------------
// Shared 128x128x(K=1024) bf16 GEMM core (m97 structure).
// ---------------------------------------------------------------------------
__device__ __forceinline__ void gemm_core(const unsigned short* __restrict__ A,
                                          const unsigned short* __restrict__ Bt,
                                          int brow, int bcol,
                                          unsigned short* As, unsigned short* Bs,
                                          f32x4 (&acc)[4][4]) {
    const int tid = threadIdx.x;
    const int w = tid >> 6, lane = tid & 63;
    const int g = lane >> 4, c = lane & 15;
    const int wr = (w >> 1) * 64, wc = (w & 1) * 64;

    for (int k0 = 0; k0 < 1024; k0 += 64) {
        __syncthreads();
#pragma unroll
        for (int i = 0; i < 4; i++) {
            int slot = i * 256 + tid;
            int row = slot >> 3, sub = slot & 7;
            int koff = k0 + ((sub ^ (row & 7)) << 3);
            GLL(A + (size_t)(brow + row) * 1024 + koff, As + (size_t)(i * 256 + w * 64) * 8);
            GLL(Bt + (size_t)(bcol + row) * 1024 + koff, Bs + (size_t)(i * 256 + w * 64) * 8);
        }
        __syncthreads();
#pragma unroll
        for (int kc = 0; kc < 2; kc++) {
            short8 a[4], b[4];
#pragma unroll
            for (int f = 0; f < 4; f++) {
                int rowA = wr + f * 16 + c;
                a[f] = *(const short8*)(As + (size_t)(rowA * 8 + ((kc * 4 + g) ^ (rowA & 7))) * 8);
                int rowB = wc + f * 16 + c;
                b[f] = *(const short8*)(Bs + (size_t)(rowB * 8 + ((kc * 4 + g) ^ (rowB & 7))) * 8);
            }
#pragma unroll
            for (int fi = 0; fi < 4; fi++)
#pragma unroll
                for (int fj = 0; fj < 4; fj++)
                    acc[fi][fj] = __builtin_amdgcn_mfma_f32_16x16x32_bf16(a[fi], b[fj], acc[fi][fj], 0, 0, 0);
        }
    }
}

// GEMM1: X[8192,1024] @ Wqkv -> q,k into qkv[8192,2048] (bf16), v transposed
// into vt[(b*16+h)*64+d][4096] (bf16).
__global__ __launch_bounds__(256) void gemm_qkv(const unsigned short* __restrict__ A,
                                                const unsigned short* __restrict__ Bt,
                                                unsigned short* __restrict__ qkv,
                                                unsigned short* __restrict__ vt) {
    __shared__ unsigned short As[128 * 64];
    __shared__ unsigned short Bs[128 * 64];
    const int tid = threadIdx.x;
    const int lane = tid & 63, w = tid >> 6;
    const int g = lane >> 4, c = lane & 15;
    const int brow = blockIdx.x * 128, bcol = blockIdx.y * 128;
    const int wr = (w >> 1) * 64, wc = (w & 1) * 64;

    f32x4 acc[4][4];
#pragma unroll
    for (int i = 0; i < 4; i++)
#pragma unroll
        for (int j = 0; j < 4; j++) acc[i][j] = (f32x4){0.f, 0.f, 0.f, 0.f};

    gemm_core(A, Bt, brow, bcol, As, Bs, acc);

    if (bcol < 2048) {  // q or k region -> qkv buffer
#pragma unroll
        for (int fi = 0; fi < 4; fi++) {
            int row = brow + wr + fi * 16 + g * 4;
#pragma unroll
            for (int fj = 0; fj < 4; fj++) {
                int col = bcol + wc + fj * 16 + c;
#pragma unroll
                for (int r = 0; r < 4; r++)
                    qkv[(size_t)(row + r) * 2048 + col] = f2bf(acc[fi][fj][r]);
            }
        }
    } else {  // v region -> transposed vt, 4 tokens packed per 8B store
        int b = brow >> 12;
        int nbase = (brow & 4095) + wr;
#pragma unroll
        for (int fi = 0; fi < 4; fi++) {
            int n0 = nbase + fi * 16 + g * 4;
#pragma unroll
            for (int fj = 0; fj < 4; fj++) {
                int hd = bcol - 2048 + wc + fj * 16 + c;
                us4 pk;
#pragma unroll
                for (int r = 0; r < 4; r++) pk[r] = f2bf(acc[fi][fj][r]);
                *(us4*)(vt + (size_t)(b * 1024 + hd) * 4096 + n0) = pk;
            }
        }
    }
}

// GEMM2: attn[8192,1024] @ Wout -> out fp32 [8192,1024]
__global__ __launch_bounds__(256) void gemm_out(const unsigned short* __restrict__ A,
                                                const unsigned short* __restrict__ Bt,
                                                float* __restrict__ C) {
    __shared__ unsigned short As[128 * 64];
    __shared__ unsigned short Bs[128 * 64];
    const int tid = threadIdx.x;
    const int lane = tid & 63, w = tid >> 6;
    const int g = lane >> 4, c = lane & 15;
    const int brow = blockIdx.x * 128, bcol = blockIdx.y * 128;
    const int wr = (w >> 1) * 64, wc = (w & 1) * 64;

    f32x4 acc[4][4];
#pragma unroll
    for (int i = 0; i < 4; i++)
#pragma unroll
        for (int j = 0; j < 4; j++) acc[i][j] = (f32x4){0.f, 0.f, 0.f, 0.f};

    gemm_core(A, Bt, brow, bcol, As, Bs, acc);

#pragma unroll
    for (int fi = 0; fi < 4; fi++) {
        int row = brow + wr + fi * 16 + g * 4;
#pragma unroll
        for (int fj = 0; fj < 4; fj++) {
            int col = bcol + wc + fj * 16 + c;
#pragma unroll
            for (int r = 0; r < 4; r++)
                C[(size_t)(row + r) * 1024 + col] = acc[fi][fj][r];
        }
    }
}

// ---------------------------------------------------------------------------
// per-(token,head) RMSNorm + RoPE on q and k, in place.
// ---------------------------------------------------------------------------
__global__ __launch_bounds__(256) void norm_rope(unsigned short* __restrict__ qkv,
                                                 const float* __restrict__ cosb,
                                                 const float* __restrict__ sinb,
                                                 const float* __restrict__ gq,
                                                 const float* __restrict__ gk) {
    int u = blockIdx.x * 4 + (threadIdx.x >> 6);
    int lane = threadIdx.x & 63;
    int t = u >> 5, rest = u & 31, h = rest >> 1, qk = rest & 1;
    int n = t & 4095;
    unsigned short* p = qkv + (size_t)t * 2048 + qk * 1024 + h * 64 + lane;
    float x = bf2f(*p);
    float ss = x * x;
#pragma unroll
    for (int m = 1; m < 64; m <<= 1) ss += __shfl_xor(ss, m, 64);
    float rr = rsqrtf(ss * 0.015625f + 1e-6f);
    float xn = x * rr * (qk ? gk[lane] : gq[lane]);
    float other = __shfl_xor(xn, 32, 64);
    float cv = cosb[n * 64 + lane], sv = sinb[n * 64 + lane];
    float rh = (lane < 32) ? -other : other;
    *p = f2bf(xn * cv + rh * sv);
}

// ---------------------------------------------------------------------------
// Flash attention v3: swapped QK^T on 32x32x16, in-register softmax with
// raw v_exp (builtin), cvt_pk P-packing (T12), defer-max (T13), tree
// reductions, setprio around MFMA clusters (T5).
// Grid: 512 blocks (XCD-chunk remapped), 4 waves x 64 q-rows = 256 q/block.
// ---------------------------------------------------------------------------
__global__ __launch_bounds__(256, 2) void attn_fwd(const unsigned short* __restrict__ qkv,
                                                   const unsigned short* __restrict__ vt,
                                                   unsigned short* __restrict__ attn) {
    __shared__ unsigned short Ks[2][4096];  // [buf][(dslice*64+kv)*8]
    __shared__ unsigned short Vs[2][4096];  // [buf][(kvslice*64+d)*8]
    const int tid = threadIdx.x;
    const int w = tid >> 6, lane = tid & 63;
    const int c31 = lane & 31, hi = lane >> 5;

    // XCD-chunked bijective remap: 512 blocks, 64 per XCD, bh-major chunks.
    int logical = (blockIdx.x & 7) * 64 + (blockIdx.x >> 3);
    const int bh = logical >> 4, qt = logical & 15;
    const int b = bh >> 4, h = bh & 15;
    const size_t tokbase = (size_t)b * 4096;
    const int q0 = qt * 256 + w * 64;

    // Q fragments [qsub][slice], pre-scaled by 0.125 (exact in bf16)
    short8 qf[2][4];
#pragma unroll
    for (int qs = 0; qs < 2; qs++)
#pragma unroll
        for (int sl = 0; sl < 4; sl++) {
            const unsigned short* src =
                qkv + (tokbase + q0 + qs * 32 + c31) * 2048 + h * 64 + sl * 16 + hi * 8;
            short8 v = *(const short8*)src;
#pragma unroll
            for (int j = 0; j < 8; j++)
                v[j] = (short)f2bf(bf2f((unsigned short)v[j]) * 0.125f);
            qf[qs][sl] = v;
        }

    f32x16 o[2][2];  // [qsub][dsub], O^T[d][q]
#pragma unroll
    for (int qs = 0; qs < 2; qs++)
#pragma unroll
        for (int ds = 0; ds < 2; ds++)
#pragma unroll
            for (int r = 0; r < 16; r++) o[qs][ds][r] = 0.f;
    float m_run[2] = {-__builtin_inff(), -__builtin_inff()};
    float l_run[2] = {0.f, 0.f};

    // stage tile (kv0) into buffer bi: wave w handles slices {w, 4+w}
#define STAGE_KV(bi, kv0)                                                                     \
    {                                                                                          \
        _Pragma("unroll") for (int i = 0; i < 2; i++) {                                        \
            int s2 = i * 4 + w;                                                                \
            GLL(qkv + (tokbase + (kv0) + lane) * 2048 + 1024 + h * 64 + s2 * 8,                \
                &Ks[bi][(size_t)s2 * 512]);                                                    \
            GLL(vt + ((size_t)(bh * 64 + lane)) * 4096 + (kv0) + s2 * 8,                       \
                &Vs[bi][(size_t)s2 * 512]);                                                    \
        }                                                                                      \
    }

    STAGE_KV(0, 0);
    int cur = 0;

    for (int t = 0; t < 64; t++) {
        __syncthreads();  // stage(cur) visible; prev reads done
        if (t < 63) STAGE_KV(cur ^ 1, (t + 1) * 64);

        // ---- K fragments + QK^T (S[kv][q], swapped) ----
        short8 kf[2][4];
#pragma unroll
        for (int m = 0; m < 2; m++)
#pragma unroll
            for (int sl = 0; sl < 4; sl++)
                kf[m][sl] = *(const short8*)&Ks[cur][(size_t)(((sl * 2 + hi) * 64) + m * 32 + c31) * 8];

        f32x16 sacc[2][2];
        __builtin_amdgcn_s_setprio(1);
#pragma unroll
        for (int qs = 0; qs < 2; qs++)
#pragma unroll
            for (int m = 0; m < 2; m++) {
                f32x16 a;
#pragma unroll
                for (int r = 0; r < 16; r++) a[r] = 0.f;
#pragma unroll
                for (int sl = 0; sl < 4; sl++)
                    a = __builtin_amdgcn_mfma_f32_32x32x16_bf16(kf[m][sl], qf[qs][sl], a, 0, 0, 0);
                sacc[qs][m] = a;
            }
        __builtin_amdgcn_s_setprio(0);

        // ---- softmax + P pack per qsub ----
        short8 pf[2][4];  // [qsub][kvslice] B-operand fragments
#pragma unroll
        for (int qs = 0; qs < 2; qs++) {
            // tile max, tree (depth 5)
            f32x16 t16;
#pragma unroll
            for (int r = 0; r < 16; r++) t16[r] = fmaxf(sacc[qs][0][r], sacc[qs][1][r]);
#pragma unroll
            for (int st = 8; st > 0; st >>= 1)
#pragma unroll
                for (int j = 0; j < st; j++) t16[j] = fmaxf(t16[j], t16[j + st]);
            float mx = fmaxf(t16[0], __shfl_xor(t16[0], 32, 64));

            // defer-max (T13): only rescale when max grew materially
            if (__any(mx > m_run[qs] + 4.0f)) {
                float mn = fmaxf(m_run[qs], mx);
                float alpha = __builtin_amdgcn_exp2f((m_run[qs] - mn) * LOG2E);
                m_run[qs] = mn;
                l_run[qs] *= alpha;
#pragma unroll
                for (int ds = 0; ds < 2; ds++)
#pragma unroll
                    for (int r = 0; r < 16; r++) o[qs][ds][r] *= alpha;
            }
            float nb = -m_run[qs] * LOG2E;

            // exp in place (raw v_exp_f32)
#pragma unroll
            for (int m = 0; m < 2; m++)
#pragma unroll
                for (int r = 0; r < 16; r++)
                    sacc[qs][m][r] = __builtin_amdgcn_exp2f(fmaf(sacc[qs][m][r], LOG2E, nb));

            // row sum, tree
#pragma unroll
            for (int r = 0; r < 16; r++) t16[r] = sacc[qs][0][r] + sacc[qs][1][r];
#pragma unroll
            for (int st = 8; st > 0; st >>= 1)
#pragma unroll
                for (int j = 0; j < st; j++) t16[j] += t16[j + st];
            l_run[qs] += t16[0] + __shfl_xor(t16[0], 32, 64);

            // pack pairs via v_cvt_pk_bf16_f32 (T12), then exchange halves
#pragma unroll
            for (int m = 0; m < 2; m++) {
                unsigned int q2[8];
#pragma unroll
                for (int w8 = 0; w8 < 8; w8++) {
                    unsigned int r_;
                    asm("v_cvt_pk_bf16_f32 %0, %1, %2"
                        : "=v"(r_)
                        : "v"(sacc[qs][m][2 * w8]), "v"(sacc[qs][m][2 * w8 + 1]));
                    q2[w8] = r_;
                }
                unsigned int x0 = hi ? q2[0] : q2[2];
                unsigned int x1 = hi ? q2[1] : q2[3];
                unsigned int x2 = hi ? q2[4] : q2[6];
                unsigned int x3 = hi ? q2[5] : q2[7];
                unsigned int r0 = (unsigned int)__shfl_xor((int)x0, 32, 64);
                unsigned int r1 = (unsigned int)__shfl_xor((int)x1, 32, 64);
                unsigned int r2 = (unsigned int)__shfl_xor((int)x2, 32, 64);
                unsigned int r3 = (unsigned int)__shfl_xor((int)x3, 32, 64);
                union { unsigned int u[4]; short8 s; } f0, f1;
                f0.u[0] = hi ? r0 : q2[0];
                f0.u[1] = hi ? r1 : q2[1];
                f0.u[2] = hi ? q2[2] : r0;
                f0.u[3] = hi ? q2[3] : r1;
                f1.u[0] = hi ? r2 : q2[4];
                f1.u[1] = hi ? r3 : q2[5];
                f1.u[2] = hi ? q2[6] : r2;
                f1.u[3] = hi ? q2[7] : r3;
                pf[qs][2 * m] = f0.s;
                pf[qs][2 * m + 1] = f1.s;
            }
        }

        // ---- PV: O^T[d][q] += V^T[d][kv] . P ----
        __builtin_amdgcn_s_setprio(1);
#pragma unroll
        for (int ds = 0; ds < 2; ds++)
#pragma unroll
            for (int kvs = 0; kvs < 4; kvs++) {
                short8 vf = *(const short8*)&Vs[cur][(size_t)(((kvs * 2 + hi) * 64) + ds * 32 + c31) * 8];
                o[0][ds] = __builtin_amdgcn_mfma_f32_32x32x16_bf16(vf, pf[0][kvs], o[0][ds], 0, 0, 0);
                o[1][ds] = __builtin_amdgcn_mfma_f32_32x32x16_bf16(vf, pf[1][kvs], o[1][ds], 0, 0, 0);
            }
        __builtin_amdgcn_s_setprio(0);
        cur ^= 1;
    }

    // ---- epilogue: O/l -> attn[token][h*64+d] bf16 ----
#pragma unroll
    for (int qs = 0; qs < 2; qs++) {
        float inv = 1.f / l_run[qs];
        int token = q0 + qs * 32 + c31;
#pragma unroll
        for (int ds = 0; ds < 2; ds++)
#pragma unroll
            for (int rb = 0; rb < 4; rb++) {
                us4 pk;
#pragma unroll
                for (int j = 0; j < 4; j++) pk[j] = f2bf(o[qs][ds][rb * 4 + j] * inv);
                *(us4*)(attn + (tokbase + token) * 1024 + h * 64 + ds * 32 + rb * 8 + hi * 4) = pk;
            }
    }
#undef STAGE_KV
}

// ---------------------------------------------------------------------------
extern "C" void kernel_launch(void* const* d_in, const int* in_sizes, int n_in,
                              void* d_out, int out_size, void* d_ws, size_t ws_size,
                              hipStream_t stream) {
    const float* hs   = (const float*)d_in[0];
    const float* cosb = (const float*)d_in[1];
    const float* sinb = (const float*)d_in[2];
    const float* wqkv = (const float*)d_in[3];
    const float* wout = (const float*)d_in[4];
    const float* gq   = (const float*)d_in[5];
    const float* gk   = (const float*)d_in[6];
    float* out = (float*)d_out;

    char* ws = (char*)d_ws;
    unsigned short* Xb    = (unsigned short*)(ws);               // 8192*1024*2  = 16 MiB
    unsigned short* WqkvT = (unsigned short*)(ws + 16777216);    // 3072*1024*2  =  6 MiB
    unsigned short* WoutT = (unsigned short*)(ws + 23068672);    // 1024*1024*2  =  2 MiB
    unsigned short* qkv   = (unsigned short*)(ws + 25165824);    // 8192*2048*2  = 32 MiB
    unsigned short* vt    = (unsigned short*)(ws + 58720256);    // 2048*4096*2  = 16 MiB
    unsigned short* attn  = (unsigned short*)(ws + 75497472);    // 8192*1024*2  = 16 MiB

    conv_bf16<<<4096, 256, 0, stream>>>((const float4*)hs, (us4*)Xb, (8192 * 1024) / 4);
    transpose_w<<<dim3(48, 16), 256, 0, stream>>>(wqkv, WqkvT, 1024, 3072);
    transpose_w<<<dim3(16, 16), 256, 0, stream>>>(wout, WoutT, 1024, 1024);
    gemm_qkv<<<dim3(64, 24), 256, 0, stream>>>(Xb, WqkvT, qkv, vt);
    norm_rope<<<65536, 256, 0, stream>>>(qkv, cosb, sinb, gq, gk);
    attn_fwd<<<512, 256, 0, stream>>>(qkv, vt, attn);
    gemm_out<<<dim3(64, 8), 256, 0, stream>>>(attn, WoutT, out);
}

// Round 7
// 416.686 us; speedup vs baseline: 2.1739x; 1.0057x over previous
//
#include <hip/hip_runtime.h>
#include <hip/hip_bf16.h>
#include <stdint.h>

#define LOG2E 1.44269504088896340736f

typedef __attribute__((ext_vector_type(8))) short short8;
typedef __attribute__((ext_vector_type(4))) float f32x4;
typedef __attribute__((ext_vector_type(16))) float f32x16;
typedef __attribute__((ext_vector_type(4))) unsigned short us4;

static __device__ __forceinline__ float bf2f(unsigned short u) {
    union { unsigned int i; float f; } v; v.i = ((unsigned int)u) << 16; return v.f;
}
static __device__ __forceinline__ unsigned short f2bf(float f) {
    __hip_bfloat16 h = __float2bfloat16(f);
    union { __hip_bfloat16 h; unsigned short u; } v; v.h = h; return v.u;
}

// global -> LDS direct copy, 16B per lane. LDS dest is wave-uniform base
// (+ lane*16 implicit); global source is per-lane (guide §5, m104/m173).
#define GLL(gsrc, ldst) \
    __builtin_amdgcn_global_load_lds((const __attribute__((address_space(1))) unsigned int*)(gsrc), \
                                     (__attribute__((address_space(3))) unsigned int*)(ldst), 16, 0, 0)

// ---------------------------------------------------------------------------
// fp32 -> bf16 convert (vectorized)
// ---------------------------------------------------------------------------
__global__ __launch_bounds__(256) void conv_bf16(const float4* __restrict__ in,
                                                 us4* __restrict__ out, int n4) {
    int i = blockIdx.x * blockDim.x + threadIdx.x;
    int stride = gridDim.x * blockDim.x;
    for (; i < n4; i += stride) {
        float4 v = in[i];
        us4 o;
        o[0] = f2bf(v.x); o[1] = f2bf(v.y); o[2] = f2bf(v.z); o[3] = f2bf(v.w);
        out[i] = o;
    }
}

// ---------------------------------------------------------------------------
// W [K][M] fp32 -> WT [M][K] bf16 (64x64 tiles via LDS, padded)
// ---------------------------------------------------------------------------
__global__ __launch_bounds__(256) void transpose_w(const float* __restrict__ W,
                                                   unsigned short* __restrict__ WT,
                                                   int K, int M) {
    __shared__ unsigned short T[64][65];
    int m0 = blockIdx.x * 64, k0 = blockIdx.y * 64;
    int r = threadIdx.x >> 2, q = (threadIdx.x & 3) * 16;
    const float4* src = (const float4*)(W + (size_t)(k0 + r) * M + m0 + q);
#pragma unroll
    for (int j = 0; j < 4; j++) {
        float4 v = src[j];
        T[r][q + j * 4 + 0] = f2bf(v.x);
        T[r][q + j * 4 + 1] = f2bf(v.y);
        T[r][q + j * 4 + 2] = f2bf(v.z);
        T[r][q + j * 4 + 3] = f2bf(v.w);
    }
    __syncthreads();
    unsigned short tmp[16];
#pragma unroll
    for (int j = 0; j < 16; j++) tmp[j] = T[q + j][r];
    unsigned short* dst = WT + (size_t)(m0 + r) * K + k0 + q;
    *(short8*)dst = *(const short8*)tmp;
    *(short8*)(dst + 8) = *(const short8*)(tmp + 8);
}

// ---------------------------------------------------------------------------
// Shared 128x128x(K=1024) bf16 GEMM core (m97 structure).
// ---------------------------------------------------------------------------
__device__ __forceinline__ void gemm_core(const unsigned short* __restrict__ A,
                                          const unsigned short* __restrict__ Bt,
                                          int brow, int bcol,
                                          unsigned short* As, unsigned short* Bs,
                                          f32x4 (&acc)[4][4]) {
    const int tid = threadIdx.x;
    const int w = tid >> 6, lane = tid & 63;
    const int g = lane >> 4, c = lane & 15;
    const int wr = (w >> 1) * 64, wc = (w & 1) * 64;

    for (int k0 = 0; k0 < 1024; k0 += 64) {
        __syncthreads();
#pragma unroll
        for (int i = 0; i < 4; i++) {
            int slot = i * 256 + tid;
            int row = slot >> 3, sub = slot & 7;
            int koff = k0 + ((sub ^ (row & 7)) << 3);
            GLL(A + (size_t)(brow + row) * 1024 + koff, As + (size_t)(i * 256 + w * 64) * 8);
            GLL(Bt + (size_t)(bcol + row) * 1024 + koff, Bs + (size_t)(i * 256 + w * 64) * 8);
        }
        __syncthreads();
#pragma unroll
        for (int kc = 0; kc < 2; kc++) {
            short8 a[4], b[4];
#pragma unroll
            for (int f = 0; f < 4; f++) {
                int rowA = wr + f * 16 + c;
                a[f] = *(const short8*)(As + (size_t)(rowA * 8 + ((kc * 4 + g) ^ (rowA & 7))) * 8);
                int rowB = wc + f * 16 + c;
                b[f] = *(const short8*)(Bs + (size_t)(rowB * 8 + ((kc * 4 + g) ^ (rowB & 7))) * 8);
            }
#pragma unroll
            for (int fi = 0; fi < 4; fi++)
#pragma unroll
                for (int fj = 0; fj < 4; fj++)
                    acc[fi][fj] = __builtin_amdgcn_mfma_f32_16x16x32_bf16(a[fi], b[fj], acc[fi][fj], 0, 0, 0);
        }
    }
}

// GEMM1: X[8192,1024] @ Wqkv -> q,k into qkv[8192,2048] (bf16), v transposed
// into vt[(b*16+h)*64+d][4096] (bf16).
__global__ __launch_bounds__(256) void gemm_qkv(const unsigned short* __restrict__ A,
                                                const unsigned short* __restrict__ Bt,
                                                unsigned short* __restrict__ qkv,
                                                unsigned short* __restrict__ vt) {
    __shared__ unsigned short As[128 * 64];
    __shared__ unsigned short Bs[128 * 64];
    const int tid = threadIdx.x;
    const int lane = tid & 63, w = tid >> 6;
    const int g = lane >> 4, c = lane & 15;
    const int brow = blockIdx.x * 128, bcol = blockIdx.y * 128;
    const int wr = (w >> 1) * 64, wc = (w & 1) * 64;

    f32x4 acc[4][4];
#pragma unroll
    for (int i = 0; i < 4; i++)
#pragma unroll
        for (int j = 0; j < 4; j++) acc[i][j] = (f32x4){0.f, 0.f, 0.f, 0.f};

    gemm_core(A, Bt, brow, bcol, As, Bs, acc);

    if (bcol < 2048) {  // q or k region -> qkv buffer
#pragma unroll
        for (int fi = 0; fi < 4; fi++) {
            int row = brow + wr + fi * 16 + g * 4;
#pragma unroll
            for (int fj = 0; fj < 4; fj++) {
                int col = bcol + wc + fj * 16 + c;
#pragma unroll
                for (int r = 0; r < 4; r++)
                    qkv[(size_t)(row + r) * 2048 + col] = f2bf(acc[fi][fj][r]);
            }
        }
    } else {  // v region -> transposed vt, 4 tokens packed per 8B store
        int b = brow >> 12;
        int nbase = (brow & 4095) + wr;
#pragma unroll
        for (int fi = 0; fi < 4; fi++) {
            int n0 = nbase + fi * 16 + g * 4;
#pragma unroll
            for (int fj = 0; fj < 4; fj++) {
                int hd = bcol - 2048 + wc + fj * 16 + c;
                us4 pk;
#pragma unroll
                for (int r = 0; r < 4; r++) pk[r] = f2bf(acc[fi][fj][r]);
                *(us4*)(vt + (size_t)(b * 1024 + hd) * 4096 + n0) = pk;
            }
        }
    }
}

// GEMM2: attn[8192,1024] @ Wout -> out fp32 [8192,1024]
__global__ __launch_bounds__(256) void gemm_out(const unsigned short* __restrict__ A,
                                                const unsigned short* __restrict__ Bt,
                                                float* __restrict__ C) {
    __shared__ unsigned short As[128 * 64];
    __shared__ unsigned short Bs[128 * 64];
    const int tid = threadIdx.x;
    const int lane = tid & 63, w = tid >> 6;
    const int g = lane >> 4, c = lane & 15;
    const int brow = blockIdx.x * 128, bcol = blockIdx.y * 128;
    const int wr = (w >> 1) * 64, wc = (w & 1) * 64;

    f32x4 acc[4][4];
#pragma unroll
    for (int i = 0; i < 4; i++)
#pragma unroll
        for (int j = 0; j < 4; j++) acc[i][j] = (f32x4){0.f, 0.f, 0.f, 0.f};

    gemm_core(A, Bt, brow, bcol, As, Bs, acc);

#pragma unroll
    for (int fi = 0; fi < 4; fi++) {
        int row = brow + wr + fi * 16 + g * 4;
#pragma unroll
        for (int fj = 0; fj < 4; fj++) {
            int col = bcol + wc + fj * 16 + c;
#pragma unroll
            for (int r = 0; r < 4; r++)
                C[(size_t)(row + r) * 1024 + col] = acc[fi][fj][r];
        }
    }
}

// ---------------------------------------------------------------------------
// per-(token,head) RMSNorm + RoPE on q and k, in place.
// ---------------------------------------------------------------------------
__global__ __launch_bounds__(256) void norm_rope(unsigned short* __restrict__ qkv,
                                                 const float* __restrict__ cosb,
                                                 const float* __restrict__ sinb,
                                                 const float* __restrict__ gq,
                                                 const float* __restrict__ gk) {
    int u = blockIdx.x * 4 + (threadIdx.x >> 6);
    int lane = threadIdx.x & 63;
    int t = u >> 5, rest = u & 31, h = rest >> 1, qk = rest & 1;
    int n = t & 4095;
    unsigned short* p = qkv + (size_t)t * 2048 + qk * 1024 + h * 64 + lane;
    float x = bf2f(*p);
    float ss = x * x;
#pragma unroll
    for (int m = 1; m < 64; m <<= 1) ss += __shfl_xor(ss, m, 64);
    float rr = rsqrtf(ss * 0.015625f + 1e-6f);
    float xn = x * rr * (qk ? gk[lane] : gq[lane]);
    float other = __shfl_xor(xn, 32, 64);
    float cv = cosb[n * 64 + lane], sv = sinb[n * 64 + lane];
    float rh = (lane < 32) ? -other : other;
    *p = f2bf(xn * cv + rh * sv);
}

// ---------------------------------------------------------------------------
// Flash attention v4: v3 softmax (raw exp, cvt_pk, defer-max, trees, setprio)
// at doubled occupancy: 128 q/block (1 qsub/wave), 1024 blocks = 4 blocks/CU
// = 4 waves/SIMD from independent blocks (no shared barriers -> phase
// diversity; VALU of one wave overlaps MFMA of others).
// ---------------------------------------------------------------------------
__global__ __launch_bounds__(256, 4) void attn_fwd(const unsigned short* __restrict__ qkv,
                                                   const unsigned short* __restrict__ vt,
                                                   unsigned short* __restrict__ attn) {
    __shared__ unsigned short Ks[2][4096];  // [buf][(dslice*64+kv)*8]
    __shared__ unsigned short Vs[2][4096];  // [buf][(kvslice*64+d)*8]
    const int tid = threadIdx.x;
    const int w = tid >> 6, lane = tid & 63;
    const int c31 = lane & 31, hi = lane >> 5;

    // XCD-chunked bijective remap: 1024 blocks, 128 per XCD, bh-major chunks
    // (4 heads per XCD -> 4MB K/V working set fits the 4MB XCD L2).
    int logical = (blockIdx.x & 7) * 128 + (blockIdx.x >> 3);
    const int bh = logical >> 5, qt = logical & 31;
    const int b = bh >> 4, h = bh & 15;
    const size_t tokbase = (size_t)b * 4096;
    const int q0 = qt * 128 + w * 32;

    // Q fragments [slice], pre-scaled by 0.125 (exact in bf16)
    short8 qf[4];
#pragma unroll
    for (int sl = 0; sl < 4; sl++) {
        const unsigned short* src =
            qkv + (tokbase + q0 + c31) * 2048 + h * 64 + sl * 16 + hi * 8;
        short8 v = *(const short8*)src;
#pragma unroll
        for (int j = 0; j < 8; j++)
            v[j] = (short)f2bf(bf2f((unsigned short)v[j]) * 0.125f);
        qf[sl] = v;
    }

    f32x16 o[2];  // [dsub], O^T[d][q]
#pragma unroll
    for (int ds = 0; ds < 2; ds++)
#pragma unroll
        for (int r = 0; r < 16; r++) o[ds][r] = 0.f;
    float m_run = -__builtin_inff();
    float l_run = 0.f;

    // stage tile (kv0) into buffer bi: wave w handles slices {w, 4+w}
#define STAGE_KV(bi, kv0)                                                                     \
    {                                                                                          \
        _Pragma("unroll") for (int i = 0; i < 2; i++) {                                        \
            int s2 = i * 4 + w;                                                                \
            GLL(qkv + (tokbase + (kv0) + lane) * 2048 + 1024 + h * 64 + s2 * 8,                \
                &Ks[bi][(size_t)s2 * 512]);                                                    \
            GLL(vt + ((size_t)(bh * 64 + lane)) * 4096 + (kv0) + s2 * 8,                       \
                &Vs[bi][(size_t)s2 * 512]);                                                    \
        }                                                                                      \
    }

    STAGE_KV(0, 0);
    int cur = 0;

    for (int t = 0; t < 64; t++) {
        __syncthreads();  // stage(cur) visible; prev reads done
        if (t < 63) STAGE_KV(cur ^ 1, (t + 1) * 64);

        // ---- K fragments + QK^T (S[kv][q], swapped) ----
        short8 kf[2][4];
#pragma unroll
        for (int m = 0; m < 2; m++)
#pragma unroll
            for (int sl = 0; sl < 4; sl++)
                kf[m][sl] = *(const short8*)&Ks[cur][(size_t)(((sl * 2 + hi) * 64) + m * 32 + c31) * 8];

        f32x16 sacc[2];
        __builtin_amdgcn_s_setprio(1);
#pragma unroll
        for (int m = 0; m < 2; m++) {
            f32x16 a;
#pragma unroll
            for (int r = 0; r < 16; r++) a[r] = 0.f;
#pragma unroll
            for (int sl = 0; sl < 4; sl++)
                a = __builtin_amdgcn_mfma_f32_32x32x16_bf16(kf[m][sl], qf[sl], a, 0, 0, 0);
            sacc[m] = a;
        }
        __builtin_amdgcn_s_setprio(0);

        // ---- softmax + P pack ----
        short8 pf[4];  // [kvslice] B-operand fragments
        {
            // tile max, tree (depth 5)
            f32x16 t16;
#pragma unroll
            for (int r = 0; r < 16; r++) t16[r] = fmaxf(sacc[0][r], sacc[1][r]);
#pragma unroll
            for (int st = 8; st > 0; st >>= 1)
#pragma unroll
                for (int j = 0; j < st; j++) t16[j] = fmaxf(t16[j], t16[j + st]);
            float mx = fmaxf(t16[0], __shfl_xor(t16[0], 32, 64));

            // defer-max (T13): only rescale when max grew materially
            if (__any(mx > m_run + 4.0f)) {
                float mn = fmaxf(m_run, mx);
                float alpha = __builtin_amdgcn_exp2f((m_run - mn) * LOG2E);
                m_run = mn;
                l_run *= alpha;
#pragma unroll
                for (int ds = 0; ds < 2; ds++)
#pragma unroll
                    for (int r = 0; r < 16; r++) o[ds][r] *= alpha;
            }
            float nb = -m_run * LOG2E;

            // exp in place (raw v_exp_f32)
#pragma unroll
            for (int m = 0; m < 2; m++)
#pragma unroll
                for (int r = 0; r < 16; r++)
                    sacc[m][r] = __builtin_amdgcn_exp2f(fmaf(sacc[m][r], LOG2E, nb));

            // row sum, tree
#pragma unroll
            for (int r = 0; r < 16; r++) t16[r] = sacc[0][r] + sacc[1][r];
#pragma unroll
            for (int st = 8; st > 0; st >>= 1)
#pragma unroll
                for (int j = 0; j < st; j++) t16[j] += t16[j + st];
            l_run += t16[0] + __shfl_xor(t16[0], 32, 64);

            // pack pairs via v_cvt_pk_bf16_f32 (T12), then exchange halves
#pragma unroll
            for (int m = 0; m < 2; m++) {
                unsigned int q2[8];
#pragma unroll
                for (int w8 = 0; w8 < 8; w8++) {
                    unsigned int r_;
                    asm("v_cvt_pk_bf16_f32 %0, %1, %2"
                        : "=v"(r_)
                        : "v"(sacc[m][2 * w8]), "v"(sacc[m][2 * w8 + 1]));
                    q2[w8] = r_;
                }
                unsigned int x0 = hi ? q2[0] : q2[2];
                unsigned int x1 = hi ? q2[1] : q2[3];
                unsigned int x2 = hi ? q2[4] : q2[6];
                unsigned int x3 = hi ? q2[5] : q2[7];
                unsigned int r0 = (unsigned int)__shfl_xor((int)x0, 32, 64);
                unsigned int r1 = (unsigned int)__shfl_xor((int)x1, 32, 64);
                unsigned int r2 = (unsigned int)__shfl_xor((int)x2, 32, 64);
                unsigned int r3 = (unsigned int)__shfl_xor((int)x3, 32, 64);
                union { unsigned int u[4]; short8 s; } f0, f1;
                f0.u[0] = hi ? r0 : q2[0];
                f0.u[1] = hi ? r1 : q2[1];
                f0.u[2] = hi ? q2[2] : r0;
                f0.u[3] = hi ? q2[3] : r1;
                f1.u[0] = hi ? r2 : q2[4];
                f1.u[1] = hi ? r3 : q2[5];
                f1.u[2] = hi ? q2[6] : r2;
                f1.u[3] = hi ? q2[7] : r3;
                pf[2 * m] = f0.s;
                pf[2 * m + 1] = f1.s;
            }
        }

        // ---- PV: O^T[d][q] += V^T[d][kv] . P ----
        __builtin_amdgcn_s_setprio(1);
#pragma unroll
        for (int ds = 0; ds < 2; ds++)
#pragma unroll
            for (int kvs = 0; kvs < 4; kvs++) {
                short8 vf = *(const short8*)&Vs[cur][(size_t)(((kvs * 2 + hi) * 64) + ds * 32 + c31) * 8];
                o[ds] = __builtin_amdgcn_mfma_f32_32x32x16_bf16(vf, pf[kvs], o[ds], 0, 0, 0);
            }
        __builtin_amdgcn_s_setprio(0);
        cur ^= 1;
    }

    // ---- epilogue: O/l -> attn[token][h*64+d] bf16 ----
    {
        float inv = 1.f / l_run;
        int token = q0 + c31;
#pragma unroll
        for (int ds = 0; ds < 2; ds++)
#pragma unroll
            for (int rb = 0; rb < 4; rb++) {
                us4 pk;
#pragma unroll
                for (int j = 0; j < 4; j++) pk[j] = f2bf(o[ds][rb * 4 + j] * inv);
                *(us4*)(attn + (tokbase + token) * 1024 + h * 64 + ds * 32 + rb * 8 + hi * 4) = pk;
            }
    }
#undef STAGE_KV
}

// ---------------------------------------------------------------------------
extern "C" void kernel_launch(void* const* d_in, const int* in_sizes, int n_in,
                              void* d_out, int out_size, void* d_ws, size_t ws_size,
                              hipStream_t stream) {
    const float* hs   = (const float*)d_in[0];
    const float* cosb = (const float*)d_in[1];
    const float* sinb = (const float*)d_in[2];
    const float* wqkv = (const float*)d_in[3];
    const float* wout = (const float*)d_in[4];
    const float* gq   = (const float*)d_in[5];
    const float* gk   = (const float*)d_in[6];
    float* out = (float*)d_out;

    char* ws = (char*)d_ws;
    unsigned short* Xb    = (unsigned short*)(ws);               // 8192*1024*2  = 16 MiB
    unsigned short* WqkvT = (unsigned short*)(ws + 16777216);    // 3072*1024*2  =  6 MiB
    unsigned short* WoutT = (unsigned short*)(ws + 23068672);    // 1024*1024*2  =  2 MiB
    unsigned short* qkv   = (unsigned short*)(ws + 25165824);    // 8192*2048*2  = 32 MiB
    unsigned short* vt    = (unsigned short*)(ws + 58720256);    // 2048*4096*2  = 16 MiB
    unsigned short* attn  = (unsigned short*)(ws + 75497472);    // 8192*1024*2  = 16 MiB

    conv_bf16<<<4096, 256, 0, stream>>>((const float4*)hs, (us4*)Xb, (8192 * 1024) / 4);
    transpose_w<<<dim3(48, 16), 256, 0, stream>>>(wqkv, WqkvT, 1024, 3072);
    transpose_w<<<dim3(16, 16), 256, 0, stream>>>(wout, WoutT, 1024, 1024);
    gemm_qkv<<<dim3(64, 24), 256, 0, stream>>>(Xb, WqkvT, qkv, vt);
    norm_rope<<<65536, 256, 0, stream>>>(qkv, cosb, sinb, gq, gk);
    attn_fwd<<<1024, 256, 0, stream>>>(qkv, vt, attn);
    gemm_out<<<dim3(64, 8), 256, 0, stream>>>(attn, WoutT, out);
}

// Round 8
// 400.433 us; speedup vs baseline: 2.2621x; 1.0406x over previous
//
#include <hip/hip_runtime.h>
#include <hip/hip_bf16.h>
#include <stdint.h>

#define LOG2E 1.44269504088896340736f

typedef __attribute__((ext_vector_type(8))) short short8;
typedef __attribute__((ext_vector_type(4))) float f32x4;
typedef __attribute__((ext_vector_type(16))) float f32x16;
typedef __attribute__((ext_vector_type(4))) unsigned short us4;

static __device__ __forceinline__ float bf2f(unsigned short u) {
    union { unsigned int i; float f; } v; v.i = ((unsigned int)u) << 16; return v.f;
}
static __device__ __forceinline__ unsigned short f2bf(float f) {
    __hip_bfloat16 h = __float2bfloat16(f);
    union { __hip_bfloat16 h; unsigned short u; } v; v.h = h; return v.u;
}

// global -> LDS direct copy, 16B per lane. LDS dest is wave-uniform base
// (+ lane*16 implicit); global source is per-lane (guide §5, m104/m173).
#define GLL(gsrc, ldst) \
    __builtin_amdgcn_global_load_lds((const __attribute__((address_space(1))) unsigned int*)(gsrc), \
                                     (__attribute__((address_space(3))) unsigned int*)(ldst), 16, 0, 0)

// ---------------------------------------------------------------------------
// fp32 -> bf16 convert (vectorized)
// ---------------------------------------------------------------------------
__global__ __launch_bounds__(256) void conv_bf16(const float4* __restrict__ in,
                                                 us4* __restrict__ out, int n4) {
    int i = blockIdx.x * blockDim.x + threadIdx.x;
    int stride = gridDim.x * blockDim.x;
    for (; i < n4; i += stride) {
        float4 v = in[i];
        us4 o;
        o[0] = f2bf(v.x); o[1] = f2bf(v.y); o[2] = f2bf(v.z); o[3] = f2bf(v.w);
        out[i] = o;
    }
}

// ---------------------------------------------------------------------------
// W [K][M] fp32 -> WT [M][K] bf16 (64x64 tiles via LDS, padded)
// ---------------------------------------------------------------------------
__global__ __launch_bounds__(256) void transpose_w(const float* __restrict__ W,
                                                   unsigned short* __restrict__ WT,
                                                   int K, int M) {
    __shared__ unsigned short T[64][65];
    int m0 = blockIdx.x * 64, k0 = blockIdx.y * 64;
    int r = threadIdx.x >> 2, q = (threadIdx.x & 3) * 16;
    const float4* src = (const float4*)(W + (size_t)(k0 + r) * M + m0 + q);
#pragma unroll
    for (int j = 0; j < 4; j++) {
        float4 v = src[j];
        T[r][q + j * 4 + 0] = f2bf(v.x);
        T[r][q + j * 4 + 1] = f2bf(v.y);
        T[r][q + j * 4 + 2] = f2bf(v.z);
        T[r][q + j * 4 + 3] = f2bf(v.w);
    }
    __syncthreads();
    unsigned short tmp[16];
#pragma unroll
    for (int j = 0; j < 16; j++) tmp[j] = T[q + j][r];
    unsigned short* dst = WT + (size_t)(m0 + r) * K + k0 + q;
    *(short8*)dst = *(const short8*)tmp;
    *(short8*)(dst + 8) = *(const short8*)(tmp + 8);
}

// ---------------------------------------------------------------------------
// Shared 128x128x(K=1024) bf16 GEMM core (m97 structure).
// ---------------------------------------------------------------------------
__device__ __forceinline__ void gemm_core(const unsigned short* __restrict__ A,
                                          const unsigned short* __restrict__ Bt,
                                          int brow, int bcol,
                                          unsigned short* As, unsigned short* Bs,
                                          f32x4 (&acc)[4][4]) {
    const int tid = threadIdx.x;
    const int w = tid >> 6, lane = tid & 63;
    const int g = lane >> 4, c = lane & 15;
    const int wr = (w >> 1) * 64, wc = (w & 1) * 64;

    for (int k0 = 0; k0 < 1024; k0 += 64) {
        __syncthreads();
#pragma unroll
        for (int i = 0; i < 4; i++) {
            int slot = i * 256 + tid;
            int row = slot >> 3, sub = slot & 7;
            int koff = k0 + ((sub ^ (row & 7)) << 3);
            GLL(A + (size_t)(brow + row) * 1024 + koff, As + (size_t)(i * 256 + w * 64) * 8);
            GLL(Bt + (size_t)(bcol + row) * 1024 + koff, Bs + (size_t)(i * 256 + w * 64) * 8);
        }
        __syncthreads();
#pragma unroll
        for (int kc = 0; kc < 2; kc++) {
            short8 a[4], b[4];
#pragma unroll
            for (int f = 0; f < 4; f++) {
                int rowA = wr + f * 16 + c;
                a[f] = *(const short8*)(As + (size_t)(rowA * 8 + ((kc * 4 + g) ^ (rowA & 7))) * 8);
                int rowB = wc + f * 16 + c;
                b[f] = *(const short8*)(Bs + (size_t)(rowB * 8 + ((kc * 4 + g) ^ (rowB & 7))) * 8);
            }
#pragma unroll
            for (int fi = 0; fi < 4; fi++)
#pragma unroll
                for (int fj = 0; fj < 4; fj++)
                    acc[fi][fj] = __builtin_amdgcn_mfma_f32_16x16x32_bf16(a[fi], b[fj], acc[fi][fj], 0, 0, 0);
        }
    }
}

// GEMM1: X[8192,1024] @ Wqkv -> q,k into qkv[8192,2048] (bf16), v transposed
// into vt[(b*16+h)*64+d][4096] (bf16).
__global__ __launch_bounds__(256) void gemm_qkv(const unsigned short* __restrict__ A,
                                                const unsigned short* __restrict__ Bt,
                                                unsigned short* __restrict__ qkv,
                                                unsigned short* __restrict__ vt) {
    __shared__ unsigned short As[128 * 64];
    __shared__ unsigned short Bs[128 * 64];
    const int tid = threadIdx.x;
    const int lane = tid & 63, w = tid >> 6;
    const int g = lane >> 4, c = lane & 15;
    const int brow = blockIdx.x * 128, bcol = blockIdx.y * 128;
    const int wr = (w >> 1) * 64, wc = (w & 1) * 64;

    f32x4 acc[4][4];
#pragma unroll
    for (int i = 0; i < 4; i++)
#pragma unroll
        for (int j = 0; j < 4; j++) acc[i][j] = (f32x4){0.f, 0.f, 0.f, 0.f};

    gemm_core(A, Bt, brow, bcol, As, Bs, acc);

    if (bcol < 2048) {  // q or k region -> qkv buffer
#pragma unroll
        for (int fi = 0; fi < 4; fi++) {
            int row = brow + wr + fi * 16 + g * 4;
#pragma unroll
            for (int fj = 0; fj < 4; fj++) {
                int col = bcol + wc + fj * 16 + c;
#pragma unroll
                for (int r = 0; r < 4; r++)
                    qkv[(size_t)(row + r) * 2048 + col] = f2bf(acc[fi][fj][r]);
            }
        }
    } else {  // v region -> transposed vt, 4 tokens packed per 8B store
        int b = brow >> 12;
        int nbase = (brow & 4095) + wr;
#pragma unroll
        for (int fi = 0; fi < 4; fi++) {
            int n0 = nbase + fi * 16 + g * 4;
#pragma unroll
            for (int fj = 0; fj < 4; fj++) {
                int hd = bcol - 2048 + wc + fj * 16 + c;
                us4 pk;
#pragma unroll
                for (int r = 0; r < 4; r++) pk[r] = f2bf(acc[fi][fj][r]);
                *(us4*)(vt + (size_t)(b * 1024 + hd) * 4096 + n0) = pk;
            }
        }
    }
}

// GEMM2: attn[8192,1024] @ Wout -> out fp32 [8192,1024]
__global__ __launch_bounds__(256) void gemm_out(const unsigned short* __restrict__ A,
                                                const unsigned short* __restrict__ Bt,
                                                float* __restrict__ C) {
    __shared__ unsigned short As[128 * 64];
    __shared__ unsigned short Bs[128 * 64];
    const int tid = threadIdx.x;
    const int lane = tid & 63, w = tid >> 6;
    const int g = lane >> 4, c = lane & 15;
    const int brow = blockIdx.x * 128, bcol = blockIdx.y * 128;
    const int wr = (w >> 1) * 64, wc = (w & 1) * 64;

    f32x4 acc[4][4];
#pragma unroll
    for (int i = 0; i < 4; i++)
#pragma unroll
        for (int j = 0; j < 4; j++) acc[i][j] = (f32x4){0.f, 0.f, 0.f, 0.f};

    gemm_core(A, Bt, brow, bcol, As, Bs, acc);

#pragma unroll
    for (int fi = 0; fi < 4; fi++) {
        int row = brow + wr + fi * 16 + g * 4;
#pragma unroll
        for (int fj = 0; fj < 4; fj++) {
            int col = bcol + wc + fj * 16 + c;
#pragma unroll
            for (int r = 0; r < 4; r++)
                C[(size_t)(row + r) * 1024 + col] = acc[fi][fj][r];
        }
    }
}

// ---------------------------------------------------------------------------
// per-(token,head) RMSNorm + RoPE on q and k, in place.
// ---------------------------------------------------------------------------
__global__ __launch_bounds__(256) void norm_rope(unsigned short* __restrict__ qkv,
                                                 const float* __restrict__ cosb,
                                                 const float* __restrict__ sinb,
                                                 const float* __restrict__ gq,
                                                 const float* __restrict__ gk) {
    int u = blockIdx.x * 4 + (threadIdx.x >> 6);
    int lane = threadIdx.x & 63;
    int t = u >> 5, rest = u & 31, h = rest >> 1, qk = rest & 1;
    int n = t & 4095;
    unsigned short* p = qkv + (size_t)t * 2048 + qk * 1024 + h * 64 + lane;
    float x = bf2f(*p);
    float ss = x * x;
#pragma unroll
    for (int m = 1; m < 64; m <<= 1) ss += __shfl_xor(ss, m, 64);
    float rr = rsqrtf(ss * 0.015625f + 1e-6f);
    float xn = x * rr * (qk ? gk[lane] : gq[lane]);
    float other = __shfl_xor(xn, 32, 64);
    float cv = cosb[n * 64 + lane], sv = sinb[n * 64 + lane];
    float rh = (lane < 32) ? -other : other;
    *p = f2bf(xn * cv + rh * sv);
}

// ---------------------------------------------------------------------------
// Flash attention v5: swapped QK^T on 32x32x16; STATIC-MAX softmax.
// RMSNorm bounds ||q||2,||k||2 <= 8 (D=64, g=1; RoPE norm-preserving), so
// s = q.k/8 in [-8.1, 8.1] data-independently -> P = exp2(s*0.125*log2e
// - 9*log2e), no online max, no rescale, no branches; normalization cancels
// the constant exactly. P-pack via v_cvt_pk_bf16_f32 + v_permlane32_swap
// (pure VALU, zero DS ops in softmax). 1024 blocks (4/CU), 128 q/block.
// ---------------------------------------------------------------------------
__global__ __launch_bounds__(256, 4) void attn_fwd(const unsigned short* __restrict__ qkv,
                                                   const unsigned short* __restrict__ vt,
                                                   unsigned short* __restrict__ attn) {
    __shared__ unsigned short Ks[2][4096];  // [buf][(dslice*64+kv)*8]
    __shared__ unsigned short Vs[2][4096];  // [buf][(kvslice*64+d)*8]
    const int tid = threadIdx.x;
    const int w = tid >> 6, lane = tid & 63;
    const int c31 = lane & 31, hi = lane >> 5;

    // XCD-chunked bijective remap: 1024 blocks, 128 per XCD, bh-major chunks
    // (4 heads per XCD -> 4MB K/V working set fits the 4MB XCD L2).
    int logical = (blockIdx.x & 7) * 128 + (blockIdx.x >> 3);
    const int bh = logical >> 5, qt = logical & 31;
    const int b = bh >> 4, h = bh & 15;
    const size_t tokbase = (size_t)b * 4096;
    const int q0 = qt * 128 + w * 32;

    // Q fragments [slice], raw bf16 (scale folded into exp constant)
    short8 qf[4];
#pragma unroll
    for (int sl = 0; sl < 4; sl++)
        qf[sl] = *(const short8*)(qkv + (tokbase + q0 + c31) * 2048 + h * 64 + sl * 16 + hi * 8);

    f32x16 o[2];  // [dsub], O^T[d][q]
#pragma unroll
    for (int ds = 0; ds < 2; ds++)
#pragma unroll
        for (int r = 0; r < 16; r++) o[ds][r] = 0.f;
    float l_run = 0.f;

    const float SCL = 0.125f * LOG2E;   // 1/sqrt(D) folded into exp2 arg
    const float NB = -9.0f * LOG2E;     // static max: |s|<=8.1 provable, margin to 9

    // stage tile (kv0) into buffer bi: wave w handles slices {w, 4+w}
#define STAGE_KV(bi, kv0)                                                                     \
    {                                                                                          \
        _Pragma("unroll") for (int i = 0; i < 2; i++) {                                        \
            int s2 = i * 4 + w;                                                                \
            GLL(qkv + (tokbase + (kv0) + lane) * 2048 + 1024 + h * 64 + s2 * 8,                \
                &Ks[bi][(size_t)s2 * 512]);                                                    \
            GLL(vt + ((size_t)(bh * 64 + lane)) * 4096 + (kv0) + s2 * 8,                       \
                &Vs[bi][(size_t)s2 * 512]);                                                    \
        }                                                                                      \
    }

    STAGE_KV(0, 0);
    int cur = 0;

    for (int t = 0; t < 64; t++) {
        __syncthreads();  // stage(cur) visible; prev reads done
        if (t < 63) STAGE_KV(cur ^ 1, (t + 1) * 64);

        // ---- K fragments + QK^T (S[kv][q], swapped) ----
        short8 kf[2][4];
#pragma unroll
        for (int m = 0; m < 2; m++)
#pragma unroll
            for (int sl = 0; sl < 4; sl++)
                kf[m][sl] = *(const short8*)&Ks[cur][(size_t)(((sl * 2 + hi) * 64) + m * 32 + c31) * 8];

        f32x16 sacc[2];
        __builtin_amdgcn_s_setprio(1);
#pragma unroll
        for (int m = 0; m < 2; m++) {
            f32x16 a;
#pragma unroll
            for (int r = 0; r < 16; r++) a[r] = 0.f;
#pragma unroll
            for (int sl = 0; sl < 4; sl++)
                a = __builtin_amdgcn_mfma_f32_32x32x16_bf16(kf[m][sl], qf[sl], a, 0, 0, 0);
            sacc[m] = a;
        }
        __builtin_amdgcn_s_setprio(0);

        // ---- static-max softmax: exp, sum, pack (no cross-lane until l) ----
        short8 pf[4];  // [kvslice] B-operand fragments
        {
            // exp in place (raw v_exp_f32), scale+bias fused
#pragma unroll
            for (int m = 0; m < 2; m++)
#pragma unroll
                for (int r = 0; r < 16; r++)
                    sacc[m][r] = __builtin_amdgcn_exp2f(fmaf(sacc[m][r], SCL, NB));

            // row sum, tree
            f32x16 t16;
#pragma unroll
            for (int r = 0; r < 16; r++) t16[r] = sacc[0][r] + sacc[1][r];
#pragma unroll
            for (int st = 8; st > 0; st >>= 1)
#pragma unroll
                for (int j = 0; j < st; j++) t16[j] += t16[j + st];
            // merge with partner lane (lane^32) via permlane32_swap (no DS)
            {
                union { float f; unsigned int u; } sa, sb;
                sa.f = t16[0]; sb.f = t16[0];
                asm("v_permlane32_swap_b32 %0, %1" : "+v"(sa.u), "+v"(sb.u));
                l_run += t16[0] + (hi ? sa.f : sb.f);
            }

            // pack pairs via v_cvt_pk_bf16_f32 then v_permlane32_swap:
            // swap(q2[0],q2[2]) yields BOTH pf dwords (lanes<32 keep lo,
            // lanes>=32 receive partner's) -- zero DS ops.
#pragma unroll
            for (int m = 0; m < 2; m++) {
                unsigned int q2[8];
#pragma unroll
                for (int w8 = 0; w8 < 8; w8++) {
                    unsigned int r_;
                    asm("v_cvt_pk_bf16_f32 %0, %1, %2"
                        : "=v"(r_)
                        : "v"(sacc[m][2 * w8]), "v"(sacc[m][2 * w8 + 1]));
                    q2[w8] = r_;
                }
                asm("v_permlane32_swap_b32 %0, %1" : "+v"(q2[0]), "+v"(q2[2]));
                asm("v_permlane32_swap_b32 %0, %1" : "+v"(q2[1]), "+v"(q2[3]));
                asm("v_permlane32_swap_b32 %0, %1" : "+v"(q2[4]), "+v"(q2[6]));
                asm("v_permlane32_swap_b32 %0, %1" : "+v"(q2[5]), "+v"(q2[7]));
                union { unsigned int u[4]; short8 s; } f0, f1;
                f0.u[0] = q2[0]; f0.u[1] = q2[1]; f0.u[2] = q2[2]; f0.u[3] = q2[3];
                f1.u[0] = q2[4]; f1.u[1] = q2[5]; f1.u[2] = q2[6]; f1.u[3] = q2[7];
                pf[2 * m] = f0.s;
                pf[2 * m + 1] = f1.s;
            }
        }

        // ---- PV: O^T[d][q] += V^T[d][kv] . P ----
        __builtin_amdgcn_s_setprio(1);
#pragma unroll
        for (int ds = 0; ds < 2; ds++)
#pragma unroll
            for (int kvs = 0; kvs < 4; kvs++) {
                short8 vf = *(const short8*)&Vs[cur][(size_t)(((kvs * 2 + hi) * 64) + ds * 32 + c31) * 8];
                o[ds] = __builtin_amdgcn_mfma_f32_32x32x16_bf16(vf, pf[kvs], o[ds], 0, 0, 0);
            }
        __builtin_amdgcn_s_setprio(0);
        cur ^= 1;
    }

    // ---- epilogue: O/l -> attn[token][h*64+d] bf16 ----
    {
        float inv = 1.f / l_run;
        int token = q0 + c31;
#pragma unroll
        for (int ds = 0; ds < 2; ds++)
#pragma unroll
            for (int rb = 0; rb < 4; rb++) {
                us4 pk;
#pragma unroll
                for (int j = 0; j < 4; j++) pk[j] = f2bf(o[ds][rb * 4 + j] * inv);
                *(us4*)(attn + (tokbase + token) * 1024 + h * 64 + ds * 32 + rb * 8 + hi * 4) = pk;
            }
    }
#undef STAGE_KV
}

// ---------------------------------------------------------------------------
extern "C" void kernel_launch(void* const* d_in, const int* in_sizes, int n_in,
                              void* d_out, int out_size, void* d_ws, size_t ws_size,
                              hipStream_t stream) {
    const float* hs   = (const float*)d_in[0];
    const float* cosb = (const float*)d_in[1];
    const float* sinb = (const float*)d_in[2];
    const float* wqkv = (const float*)d_in[3];
    const float* wout = (const float*)d_in[4];
    const float* gq   = (const float*)d_in[5];
    const float* gk   = (const float*)d_in[6];
    float* out = (float*)d_out;

    char* ws = (char*)d_ws;
    unsigned short* Xb    = (unsigned short*)(ws);               // 8192*1024*2  = 16 MiB
    unsigned short* WqkvT = (unsigned short*)(ws + 16777216);    // 3072*1024*2  =  6 MiB
    unsigned short* WoutT = (unsigned short*)(ws + 23068672);    // 1024*1024*2  =  2 MiB
    unsigned short* qkv   = (unsigned short*)(ws + 25165824);    // 8192*2048*2  = 32 MiB
    unsigned short* vt    = (unsigned short*)(ws + 58720256);    // 2048*4096*2  = 16 MiB
    unsigned short* attn  = (unsigned short*)(ws + 75497472);    // 8192*1024*2  = 16 MiB

    conv_bf16<<<4096, 256, 0, stream>>>((const float4*)hs, (us4*)Xb, (8192 * 1024) / 4);
    transpose_w<<<dim3(48, 16), 256, 0, stream>>>(wqkv, WqkvT, 1024, 3072);
    transpose_w<<<dim3(16, 16), 256, 0, stream>>>(wout, WoutT, 1024, 1024);
    gemm_qkv<<<dim3(64, 24), 256, 0, stream>>>(Xb, WqkvT, qkv, vt);
    norm_rope<<<65536, 256, 0, stream>>>(qkv, cosb, sinb, gq, gk);
    attn_fwd<<<1024, 256, 0, stream>>>(qkv, vt, attn);
    gemm_out<<<dim3(64, 8), 256, 0, stream>>>(attn, WoutT, out);
}

// Round 10
// 388.092 us; speedup vs baseline: 2.3341x; 1.0318x over previous
//
#include <hip/hip_runtime.h>
#include <hip/hip_bf16.h>
#include <stdint.h>

#define LOG2E 1.44269504088896340736f

typedef __attribute__((ext_vector_type(8))) short short8;
typedef __attribute__((ext_vector_type(4))) float f32x4;
typedef __attribute__((ext_vector_type(16))) float f32x16;
typedef __attribute__((ext_vector_type(4))) unsigned short us4;

static __device__ __forceinline__ float bf2f(unsigned short u) {
    union { unsigned int i; float f; } v; v.i = ((unsigned int)u) << 16; return v.f;
}
static __device__ __forceinline__ unsigned short f2bf(float f) {
    __hip_bfloat16 h = __float2bfloat16(f);
    union { __hip_bfloat16 h; unsigned short u; } v; v.h = h; return v.u;
}

// global -> LDS direct copy, 16B per lane. LDS dest is wave-uniform base
// (+ lane*16 implicit); global source is per-lane (guide §5, m104/m173).
#define GLL(gsrc, ldst) \
    __builtin_amdgcn_global_load_lds((const __attribute__((address_space(1))) unsigned int*)(gsrc), \
                                     (__attribute__((address_space(3))) unsigned int*)(ldst), 16, 0, 0)

// ---------------------------------------------------------------------------
// fp32 -> bf16 convert (vectorized)
// ---------------------------------------------------------------------------
__global__ __launch_bounds__(256) void conv_bf16(const float4* __restrict__ in,
                                                 us4* __restrict__ out, int n4) {
    int i = blockIdx.x * blockDim.x + threadIdx.x;
    int stride = gridDim.x * blockDim.x;
    for (; i < n4; i += stride) {
        float4 v = in[i];
        us4 o;
        o[0] = f2bf(v.x); o[1] = f2bf(v.y); o[2] = f2bf(v.z); o[3] = f2bf(v.w);
        out[i] = o;
    }
}

// ---------------------------------------------------------------------------
// W [K][M] fp32 -> WT [M][K] bf16 (64x64 tiles via LDS, padded)
// ---------------------------------------------------------------------------
__global__ __launch_bounds__(256) void transpose_w(const float* __restrict__ W,
                                                   unsigned short* __restrict__ WT,
                                                   int K, int M) {
    __shared__ unsigned short T[64][65];
    int m0 = blockIdx.x * 64, k0 = blockIdx.y * 64;
    int r = threadIdx.x >> 2, q = (threadIdx.x & 3) * 16;
    const float4* src = (const float4*)(W + (size_t)(k0 + r) * M + m0 + q);
#pragma unroll
    for (int j = 0; j < 4; j++) {
        float4 v = src[j];
        T[r][q + j * 4 + 0] = f2bf(v.x);
        T[r][q + j * 4 + 1] = f2bf(v.y);
        T[r][q + j * 4 + 2] = f2bf(v.z);
        T[r][q + j * 4 + 3] = f2bf(v.w);
    }
    __syncthreads();
    unsigned short tmp[16];
#pragma unroll
    for (int j = 0; j < 16; j++) tmp[j] = T[q + j][r];
    unsigned short* dst = WT + (size_t)(m0 + r) * K + k0 + q;
    *(short8*)dst = *(const short8*)tmp;
    *(short8*)(dst + 8) = *(const short8*)(tmp + 8);
}

// ---------------------------------------------------------------------------
// Shared 128x128x(K=1024) bf16 GEMM core (m97 structure).
// ---------------------------------------------------------------------------
__device__ __forceinline__ void gemm_core(const unsigned short* __restrict__ A,
                                          const unsigned short* __restrict__ Bt,
                                          int brow, int bcol,
                                          unsigned short* As, unsigned short* Bs,
                                          f32x4 (&acc)[4][4]) {
    const int tid = threadIdx.x;
    const int w = tid >> 6, lane = tid & 63;
    const int g = lane >> 4, c = lane & 15;
    const int wr = (w >> 1) * 64, wc = (w & 1) * 64;

    for (int k0 = 0; k0 < 1024; k0 += 64) {
        __syncthreads();
#pragma unroll
        for (int i = 0; i < 4; i++) {
            int slot = i * 256 + tid;
            int row = slot >> 3, sub = slot & 7;
            int koff = k0 + ((sub ^ (row & 7)) << 3);
            GLL(A + (size_t)(brow + row) * 1024 + koff, As + (size_t)(i * 256 + w * 64) * 8);
            GLL(Bt + (size_t)(bcol + row) * 1024 + koff, Bs + (size_t)(i * 256 + w * 64) * 8);
        }
        __syncthreads();
#pragma unroll
        for (int kc = 0; kc < 2; kc++) {
            short8 a[4], b[4];
#pragma unroll
            for (int f = 0; f < 4; f++) {
                int rowA = wr + f * 16 + c;
                a[f] = *(const short8*)(As + (size_t)(rowA * 8 + ((kc * 4 + g) ^ (rowA & 7))) * 8);
                int rowB = wc + f * 16 + c;
                b[f] = *(const short8*)(Bs + (size_t)(rowB * 8 + ((kc * 4 + g) ^ (rowB & 7))) * 8);
            }
#pragma unroll
            for (int fi = 0; fi < 4; fi++)
#pragma unroll
                for (int fj = 0; fj < 4; fj++)
                    acc[fi][fj] = __builtin_amdgcn_mfma_f32_16x16x32_bf16(a[fi], b[fj], acc[fi][fj], 0, 0, 0);
        }
    }
}

// GEMM1: X[8192,1024] @ Wqkv with FUSED per-head RMSNorm+RoPE on q/k
// (applied to fp32 accumulators; wave holds a full head: wc spans 64 cols;
// rotate-half pairs (d,d+32) = (fj,fj+2) are IN-LANE; RMS sum = 3 adds +
// 4 shfl_xor within the 16-lane c-group sharing a row).
// q,k -> qkv[8192,2048] bf16; v -> transposed vt[(b*16+h)*64+d][4096] bf16.
__global__ __launch_bounds__(256) void gemm_qkv(const unsigned short* __restrict__ A,
                                                const unsigned short* __restrict__ Bt,
                                                unsigned short* __restrict__ qkv,
                                                unsigned short* __restrict__ vt,
                                                const float* __restrict__ cosb,
                                                const float* __restrict__ sinb,
                                                const float* __restrict__ gq,
                                                const float* __restrict__ gk) {
    __shared__ unsigned short As[128 * 64];
    __shared__ unsigned short Bs[128 * 64];
    const int tid = threadIdx.x;
    const int lane = tid & 63, w = tid >> 6;
    const int g = lane >> 4, c = lane & 15;
    // XCD-chunked bijective remap: 1536 blocks, 192/XCD = 3 B-panels (768KB L2-resident)
    int bid = blockIdx.x;
    int swz = (bid & 7) * 192 + (bid >> 3);
    const int brow = (swz & 63) * 128, bcol = (swz >> 6) * 128;
    const int wr = (w >> 1) * 64, wc = (w & 1) * 64;

    f32x4 acc[4][4];
#pragma unroll
    for (int i = 0; i < 4; i++)
#pragma unroll
        for (int j = 0; j < 4; j++) acc[i][j] = (f32x4){0.f, 0.f, 0.f, 0.f};

    gemm_core(A, Bt, brow, bcol, As, Bs, acc);

    if (bcol < 2048) {  // q or k region: RMSNorm + RoPE on fp32 acc, then store
        const int qk = (bcol + wc) >> 10;  // 0=q, 1=k
        const float* gvec = qk ? gk : gq;
        float gv[4];
#pragma unroll
        for (int fj = 0; fj < 4; fj++) gv[fj] = gvec[fj * 16 + c];

#pragma unroll
        for (int fi = 0; fi < 4; fi++) {
            float ss[4];
#pragma unroll
            for (int r = 0; r < 4; r++) {
                float s = 0.f;
#pragma unroll
                for (int fj = 0; fj < 4; fj++) { float x = acc[fi][fj][r]; s = fmaf(x, x, s); }
                ss[r] = s;
            }
#pragma unroll
            for (int m = 1; m < 16; m <<= 1)
#pragma unroll
                for (int r = 0; r < 4; r++) ss[r] += __shfl_xor(ss[r], m, 64);
            int rowbase = brow + wr + fi * 16 + g * 4;
#pragma unroll
            for (int r = 0; r < 4; r++) {
                float rr = rsqrtf(ss[r] * 0.015625f + 1e-6f);
                int row = rowbase + r;
                int n = row & 4095;
                float xn[4];
#pragma unroll
                for (int fj = 0; fj < 4; fj++) xn[fj] = acc[fi][fj][r] * rr * gv[fj];
                float cv[4], sv[4];
#pragma unroll
                for (int fj = 0; fj < 4; fj++) {
                    cv[fj] = cosb[n * 64 + fj * 16 + c];
                    sv[fj] = sinb[n * 64 + fj * 16 + c];
                }
                // rotate_half: d<32: x*cos - x[d+32]*sin ; d>=32: x*cos + x[d-32]*sin
                float o0 = xn[0] * cv[0] - xn[2] * sv[0];
                float o1 = xn[1] * cv[1] - xn[3] * sv[1];
                float o2 = xn[2] * cv[2] + xn[0] * sv[2];
                float o3 = xn[3] * cv[3] + xn[1] * sv[3];
                size_t base = (size_t)row * 2048 + bcol + wc + c;
                qkv[base + 0]  = f2bf(o0);
                qkv[base + 16] = f2bf(o1);
                qkv[base + 32] = f2bf(o2);
                qkv[base + 48] = f2bf(o3);
            }
        }
    } else {  // v region -> transposed vt, 4 tokens packed per 8B store
        int b = brow >> 12;
        int nbase = (brow & 4095) + wr;
#pragma unroll
        for (int fi = 0; fi < 4; fi++) {
            int n0 = nbase + fi * 16 + g * 4;
#pragma unroll
            for (int fj = 0; fj < 4; fj++) {
                int hd = bcol - 2048 + wc + fj * 16 + c;
                us4 pk;
#pragma unroll
                for (int r = 0; r < 4; r++) pk[r] = f2bf(acc[fi][fj][r]);
                *(us4*)(vt + (size_t)(b * 1024 + hd) * 4096 + n0) = pk;
            }
        }
    }
}

// GEMM2: attn[8192,1024] @ Wout -> out fp32 [8192,1024]
__global__ __launch_bounds__(256) void gemm_out(const unsigned short* __restrict__ A,
                                                const unsigned short* __restrict__ Bt,
                                                float* __restrict__ C) {
    __shared__ unsigned short As[128 * 64];
    __shared__ unsigned short Bs[128 * 64];
    const int tid = threadIdx.x;
    const int lane = tid & 63, w = tid >> 6;
    const int g = lane >> 4, c = lane & 15;
    // XCD-chunked bijective remap: 512 blocks, 64/XCD = 1 B-panel per XCD
    int bid = blockIdx.x;
    int swz = (bid & 7) * 64 + (bid >> 3);
    const int brow = (swz & 63) * 128, bcol = (swz >> 6) * 128;
    const int wr = (w >> 1) * 64, wc = (w & 1) * 64;

    f32x4 acc[4][4];
#pragma unroll
    for (int i = 0; i < 4; i++)
#pragma unroll
        for (int j = 0; j < 4; j++) acc[i][j] = (f32x4){0.f, 0.f, 0.f, 0.f};

    gemm_core(A, Bt, brow, bcol, As, Bs, acc);

#pragma unroll
    for (int fi = 0; fi < 4; fi++) {
        int row = brow + wr + fi * 16 + g * 4;
#pragma unroll
        for (int fj = 0; fj < 4; fj++) {
            int col = bcol + wc + fj * 16 + c;
#pragma unroll
            for (int r = 0; r < 4; r++)
                C[(size_t)(row + r) * 1024 + col] = acc[fi][fj][r];
        }
    }
}

// ---------------------------------------------------------------------------
// Flash attention v5: swapped QK^T on 32x32x16; STATIC-MAX softmax.
// RMSNorm bounds ||q||2,||k||2 <= 8 (D=64, g=1; RoPE norm-preserving), so
// s = q.k/8 in [-8.1, 8.1] data-independently -> P = exp2(s*0.125*log2e
// - 9*log2e), no online max, no rescale, no branches; normalization cancels
// the constant exactly. P-pack via v_cvt_pk_bf16_f32 + v_permlane32_swap
// (pure VALU, zero DS ops in softmax). 1024 blocks (4/CU), 128 q/block.
// ---------------------------------------------------------------------------
__global__ __launch_bounds__(256, 4) void attn_fwd(const unsigned short* __restrict__ qkv,
                                                   const unsigned short* __restrict__ vt,
                                                   unsigned short* __restrict__ attn) {
    __shared__ unsigned short Ks[2][4096];  // [buf][(dslice*64+kv)*8]
    __shared__ unsigned short Vs[2][4096];  // [buf][(kvslice*64+d)*8]
    const int tid = threadIdx.x;
    const int w = tid >> 6, lane = tid & 63;
    const int c31 = lane & 31, hi = lane >> 5;

    // XCD-chunked bijective remap: 1024 blocks, 128 per XCD, bh-major chunks
    // (4 heads per XCD -> 4MB K/V working set fits the 4MB XCD L2).
    int logical = (blockIdx.x & 7) * 128 + (blockIdx.x >> 3);
    const int bh = logical >> 5, qt = logical & 31;
    const int b = bh >> 4, h = bh & 15;
    const size_t tokbase = (size_t)b * 4096;
    const int q0 = qt * 128 + w * 32;

    // Q fragments [slice], raw bf16 (scale folded into exp constant)
    short8 qf[4];
#pragma unroll
    for (int sl = 0; sl < 4; sl++)
        qf[sl] = *(const short8*)(qkv + (tokbase + q0 + c31) * 2048 + h * 64 + sl * 16 + hi * 8);

    f32x16 o[2];  // [dsub], O^T[d][q]
#pragma unroll
    for (int ds = 0; ds < 2; ds++)
#pragma unroll
        for (int r = 0; r < 16; r++) o[ds][r] = 0.f;
    float l_run = 0.f;

    const float SCL = 0.125f * LOG2E;   // 1/sqrt(D) folded into exp2 arg
    const float NB = -9.0f * LOG2E;     // static max: |s|<=8.1 provable, margin to 9

    // stage tile (kv0) into buffer bi: wave w handles slices {w, 4+w}
#define STAGE_KV(bi, kv0)                                                                     \
    {                                                                                          \
        _Pragma("unroll") for (int i = 0; i < 2; i++) {                                        \
            int s2 = i * 4 + w;                                                                \
            GLL(qkv + (tokbase + (kv0) + lane) * 2048 + 1024 + h * 64 + s2 * 8,                \
                &Ks[bi][(size_t)s2 * 512]);                                                    \
            GLL(vt + ((size_t)(bh * 64 + lane)) * 4096 + (kv0) + s2 * 8,                       \
                &Vs[bi][(size_t)s2 * 512]);                                                    \
        }                                                                                      \
    }

    STAGE_KV(0, 0);
    int cur = 0;

    for (int t = 0; t < 64; t++) {
        __syncthreads();  // stage(cur) visible; prev reads done
        if (t < 63) STAGE_KV(cur ^ 1, (t + 1) * 64);

        // ---- K fragments + QK^T (S[kv][q], swapped) ----
        short8 kf[2][4];
#pragma unroll
        for (int m = 0; m < 2; m++)
#pragma unroll
            for (int sl = 0; sl < 4; sl++)
                kf[m][sl] = *(const short8*)&Ks[cur][(size_t)(((sl * 2 + hi) * 64) + m * 32 + c31) * 8];

        f32x16 sacc[2];
        __builtin_amdgcn_s_setprio(1);
#pragma unroll
        for (int m = 0; m < 2; m++) {
            f32x16 a;
#pragma unroll
            for (int r = 0; r < 16; r++) a[r] = 0.f;
#pragma unroll
            for (int sl = 0; sl < 4; sl++)
                a = __builtin_amdgcn_mfma_f32_32x32x16_bf16(kf[m][sl], qf[sl], a, 0, 0, 0);
            sacc[m] = a;
        }
        __builtin_amdgcn_s_setprio(0);

        // ---- static-max softmax: exp, sum, pack (no cross-lane until l) ----
        short8 pf[4];  // [kvslice] B-operand fragments
        {
            // exp in place (raw v_exp_f32), scale+bias fused
#pragma unroll
            for (int m = 0; m < 2; m++)
#pragma unroll
                for (int r = 0; r < 16; r++)
                    sacc[m][r] = __builtin_amdgcn_exp2f(fmaf(sacc[m][r], SCL, NB));

            // row sum, tree
            f32x16 t16;
#pragma unroll
            for (int r = 0; r < 16; r++) t16[r] = sacc[0][r] + sacc[1][r];
#pragma unroll
            for (int st = 8; st > 0; st >>= 1)
#pragma unroll
                for (int j = 0; j < st; j++) t16[j] += t16[j + st];
            // merge with partner lane (lane^32) via permlane32_swap (no DS)
            {
                union { float f; unsigned int u; } sa, sb;
                sa.f = t16[0]; sb.f = t16[0];
                asm("v_permlane32_swap_b32 %0, %1" : "+v"(sa.u), "+v"(sb.u));
                l_run += t16[0] + (hi ? sa.f : sb.f);
            }

            // pack pairs via v_cvt_pk_bf16_f32 then v_permlane32_swap:
            // swap(q2[0],q2[2]) yields BOTH pf dwords (lanes<32 keep lo,
            // lanes>=32 receive partner's) -- zero DS ops.
#pragma unroll
            for (int m = 0; m < 2; m++) {
                unsigned int q2[8];
#pragma unroll
                for (int w8 = 0; w8 < 8; w8++) {
                    unsigned int r_;
                    asm("v_cvt_pk_bf16_f32 %0, %1, %2"
                        : "=v"(r_)
                        : "v"(sacc[m][2 * w8]), "v"(sacc[m][2 * w8 + 1]));
                    q2[w8] = r_;
                }
                asm("v_permlane32_swap_b32 %0, %1" : "+v"(q2[0]), "+v"(q2[2]));
                asm("v_permlane32_swap_b32 %0, %1" : "+v"(q2[1]), "+v"(q2[3]));
                asm("v_permlane32_swap_b32 %0, %1" : "+v"(q2[4]), "+v"(q2[6]));
                asm("v_permlane32_swap_b32 %0, %1" : "+v"(q2[5]), "+v"(q2[7]));
                union { unsigned int u[4]; short8 s; } f0, f1;
                f0.u[0] = q2[0]; f0.u[1] = q2[1]; f0.u[2] = q2[2]; f0.u[3] = q2[3];
                f1.u[0] = q2[4]; f1.u[1] = q2[5]; f1.u[2] = q2[6]; f1.u[3] = q2[7];
                pf[2 * m] = f0.s;
                pf[2 * m + 1] = f1.s;
            }
        }

        // ---- PV: O^T[d][q] += V^T[d][kv] . P ----
        __builtin_amdgcn_s_setprio(1);
#pragma unroll
        for (int ds = 0; ds < 2; ds++)
#pragma unroll
            for (int kvs = 0; kvs < 4; kvs++) {
                short8 vf = *(const short8*)&Vs[cur][(size_t)(((kvs * 2 + hi) * 64) + ds * 32 + c31) * 8];
                o[ds] = __builtin_amdgcn_mfma_f32_32x32x16_bf16(vf, pf[kvs], o[ds], 0, 0, 0);
            }
        __builtin_amdgcn_s_setprio(0);
        cur ^= 1;
    }

    // ---- epilogue: O/l -> attn[token][h*64+d] bf16 ----
    {
        float inv = 1.f / l_run;
        int token = q0 + c31;
#pragma unroll
        for (int ds = 0; ds < 2; ds++)
#pragma unroll
            for (int rb = 0; rb < 4; rb++) {
                us4 pk;
#pragma unroll
                for (int j = 0; j < 4; j++) pk[j] = f2bf(o[ds][rb * 4 + j] * inv);
                *(us4*)(attn + (tokbase + token) * 1024 + h * 64 + ds * 32 + rb * 8 + hi * 4) = pk;
            }
    }
#undef STAGE_KV
}

// ---------------------------------------------------------------------------
extern "C" void kernel_launch(void* const* d_in, const int* in_sizes, int n_in,
                              void* d_out, int out_size, void* d_ws, size_t ws_size,
                              hipStream_t stream) {
    const float* hs   = (const float*)d_in[0];
    const float* cosb = (const float*)d_in[1];
    const float* sinb = (const float*)d_in[2];
    const float* wqkv = (const float*)d_in[3];
    const float* wout = (const float*)d_in[4];
    const float* gq   = (const float*)d_in[5];
    const float* gk   = (const float*)d_in[6];
    float* out = (float*)d_out;

    char* ws = (char*)d_ws;
    unsigned short* Xb    = (unsigned short*)(ws);               // 8192*1024*2  = 16 MiB
    unsigned short* WqkvT = (unsigned short*)(ws + 16777216);    // 3072*1024*2  =  6 MiB
    unsigned short* WoutT = (unsigned short*)(ws + 23068672);    // 1024*1024*2  =  2 MiB
    unsigned short* qkv   = (unsigned short*)(ws + 25165824);    // 8192*2048*2  = 32 MiB
    unsigned short* vt    = (unsigned short*)(ws + 58720256);    // 2048*4096*2  = 16 MiB
    unsigned short* attn  = (unsigned short*)(ws + 75497472);    // 8192*1024*2  = 16 MiB

    conv_bf16<<<4096, 256, 0, stream>>>((const float4*)hs, (us4*)Xb, (8192 * 1024) / 4);
    transpose_w<<<dim3(48, 16), 256, 0, stream>>>(wqkv, WqkvT, 1024, 3072);
    transpose_w<<<dim3(16, 16), 256, 0, stream>>>(wout, WoutT, 1024, 1024);
    gemm_qkv<<<1536, 256, 0, stream>>>(Xb, WqkvT, qkv, vt, cosb, sinb, gq, gk);
    attn_fwd<<<1024, 256, 0, stream>>>(qkv, vt, attn);
    gemm_out<<<512, 256, 0, stream>>>(attn, WoutT, out);
}